// Round 3
// baseline (577.023 us; speedup 1.0000x reference)
//
#include <hip/hip_runtime.h>
#include <hip/hip_bf16.h>
#include <math.h>

// Problem constants (fixed by the reference)
#define MV   100000          // voxels
#define NQ   8192            // queries
#define KN   32              // neighbors per query
#define CH   256             // channels
#define NH   8               // heads
#define DHD  32              // head dim
#define FFD  512             // FF hidden
#define NG   (NQ*KN)         // 262144 gathered rows
#define QPW  37              // 15+15+7 rel-pos columns per head (q-side)
#define QPN  (NH*QPW)        // 296

typedef __bf16 bf16x8 __attribute__((ext_vector_type(8)));
typedef float  f32x4  __attribute__((ext_vector_type(4)));

__device__ __forceinline__ float bf2f(unsigned short u) {
    return __uint_as_float(((unsigned int)u) << 16);
}
__device__ __forceinline__ unsigned short f2bf(float f) {
    unsigned int x = __float_as_uint(f);
    unsigned int r = x + 0x7FFFu + ((x >> 16) & 1u);   // RNE
    return (unsigned short)(r >> 16);
}

// ---------------------------------------------------------------------------
// k_detect_mask: gather_mask may ship as int32 (0/1) or raw 1-byte bools.
// ---------------------------------------------------------------------------
__global__ __launch_bounds__(256) void k_detect_mask(const unsigned char* __restrict__ raw,
                                                     int* __restrict__ flag) {
    __shared__ int any;
    if (threadIdx.x == 0) any = 0;
    __syncthreads();
    const uint4* p = (const uint4*)raw;
    int found = 0;
    for (int i = threadIdx.x; i < NG / 16; i += 256) {
        uint4 v = p[i];
        if ((v.x | v.y | v.z | v.w) & 0xFFFFFF00u) found = 1;
    }
    if (found) any = 1;
    __syncthreads();
    if (threadIdx.x == 0) flag[0] = any;
}

// ---------------------------------------------------------------------------
// k_prep: int mask (layout-adaptive) + bf16 col-major (B-layout) weights.
// ---------------------------------------------------------------------------
__global__ __launch_bounds__(256) void k_prep(const float* __restrict__ w_k,
                                              const float* __restrict__ w_v,
                                              const float* __restrict__ w_ff1,
                                              const float* __restrict__ w_ff2,
                                              const float* __restrict__ w_proj,
                                              const void* __restrict__ mask_raw,
                                              const int* __restrict__ flag,
                                              unsigned short* __restrict__ w_kv_t,
                                              unsigned short* __restrict__ w1_t,
                                              unsigned short* __restrict__ w2_t,
                                              unsigned short* __restrict__ wp_t,
                                              int* __restrict__ mask_i) {
    int idx = blockIdx.x * 256 + threadIdx.x;       // grid 1024 -> 262144
    int byteLayout = flag[0];
    if (idx < NG) {
        int mv = byteLayout ? (int)((const unsigned char*)mask_raw)[idx]
                            : ((const int*)mask_raw)[idx];
        mask_i[idx] = (mv != 0) ? 1 : 0;
    }
    if (idx < 512 * 256) {
        int col = idx >> 8, j = idx & 255;
        float v = (col < 256) ? w_k[j * 256 + col] : w_v[j * 256 + (col - 256)];
        w_kv_t[idx] = f2bf(v);
    }
    if (idx < 512 * 256) {
        int n = idx >> 8, k = idx & 255;
        w1_t[idx] = f2bf(w_ff1[k * FFD + n]);
    }
    if (idx < 256 * 512) {
        int n = idx >> 9, k = idx & 511;
        w2_t[idx] = f2bf(w_ff2[k * CH + n]);
    }
    if (idx < 256 * 256) {
        int n = idx >> 8, k = idx & 255;
        wp_t[idx] = f2bf(w_proj[k * CH + n]);
    }
}

// ---------------------------------------------------------------------------
// k_ln: LayerNorm rows of x[nrows][256] -> bf16. One wave per row.
// ---------------------------------------------------------------------------
__global__ __launch_bounds__(256) void k_ln(const float* __restrict__ x,
                                            const float* __restrict__ g,
                                            const float* __restrict__ b,
                                            unsigned short* __restrict__ o,
                                            int nrows) {
    int wid = threadIdx.x >> 6, lane = threadIdx.x & 63;
    int row = blockIdx.x * 4 + wid;
    if (row >= nrows) return;
    const float4 v = *(const float4*)(x + (size_t)row * CH + lane * 4);
    float s  = v.x + v.y + v.z + v.w;
    float sq = v.x * v.x + v.y * v.y + v.z * v.z + v.w * v.w;
    #pragma unroll
    for (int off = 1; off < 64; off <<= 1) {
        s  += __shfl_xor(s,  off);
        sq += __shfl_xor(sq, off);
    }
    float mu  = s * (1.f / CH);
    float var = sq * (1.f / CH) - mu * mu;
    float rs  = rsqrtf(var + 1e-5f);
    float4 gv = *(const float4*)(g + lane * 4);
    float4 bv = *(const float4*)(b + lane * 4);
    ushort4 ov;
    ov.x = f2bf((v.x - mu) * rs * gv.x + bv.x);
    ov.y = f2bf((v.y - mu) * rs * gv.y + bv.y);
    ov.z = f2bf((v.z - mu) * rs * gv.z + bv.z);
    ov.w = f2bf((v.w - mu) * rs * gv.w + bv.w);
    *(ushort4*)(o + (size_t)row * CH + lane * 4) = ov;
}

// ---------------------------------------------------------------------------
// k_q: q = (ln_x[qi]+relu(pos))@w_q + b_q (fp32) + q-side rel tables qp.
// ---------------------------------------------------------------------------
__global__ __launch_bounds__(256) void k_q(const unsigned short* __restrict__ ln_x,
                                           const float* __restrict__ coords,
                                           const int* __restrict__ qidx,
                                           const float* __restrict__ w_pos,
                                           const float* __restrict__ b_pos,
                                           const float* __restrict__ w_q,
                                           const float* __restrict__ b_q,
                                           const float* __restrict__ pos_qx,
                                           const float* __restrict__ pos_qy,
                                           const float* __restrict__ pos_qz,
                                           float* __restrict__ qout,
                                           float* __restrict__ qp) {
    __shared__ float qin_s[8 * CH];
    __shared__ float q_s[8 * CH];
    int c = threadIdx.x;
    int nb = blockIdx.x * 8;
    float wp0 = w_pos[c], wp1 = w_pos[CH + c], wp2 = w_pos[2 * CH + c], bp = b_pos[c];
    #pragma unroll
    for (int qq = 0; qq < 8; qq++) {
        int n = nb + qq;
        float p = bp + coords[n * 3] * wp0 + coords[n * 3 + 1] * wp1 + coords[n * 3 + 2] * wp2;
        p = fmaxf(p, 0.f);
        int qi = qidx[n];
        qin_s[qq * CH + c] = bf2f(ln_x[(size_t)qi * CH + c]) + p;
    }
    __syncthreads();
    float acc[8];
    float bq = b_q[c];
    #pragma unroll
    for (int qq = 0; qq < 8; qq++) acc[qq] = bq;
    #pragma unroll 4
    for (int j = 0; j < CH; j++) {
        float w = w_q[j * CH + c];
        #pragma unroll
        for (int qq = 0; qq < 8; qq++) acc[qq] += qin_s[qq * CH + j] * w;
    }
    #pragma unroll
    for (int qq = 0; qq < 8; qq++) {
        qout[(size_t)(nb + qq) * CH + c] = acc[qq];
        q_s[qq * CH + c] = acc[qq];
    }
    __syncthreads();
    for (int t = threadIdx.x; t < 8 * QPN; t += 256) {
        int qq = t / QPN, u = t % QPN;
        int h = u / QPW, r = u % QPW;
        const float* tab; int rr, R;
        if (r < 15)      { tab = pos_qx; rr = r;      R = 15; }
        else if (r < 30) { tab = pos_qy; rr = r - 15; R = 15; }
        else             { tab = pos_qz; rr = r - 30; R = 7;  }
        float a = 0.f;
        const float* qrow = q_s + qq * CH + h * DHD;
        #pragma unroll
        for (int d = 0; d < DHD; d++) a += qrow[d] * tab[(h * DHD + d) * R + rr];
        qp[(size_t)(nb + qq) * QPN + u] = a;
    }
}

// ---------------------------------------------------------------------------
// k_gemm<MODE>: gathered-row GEMM over the 262144 (n,k) rows.
// Tile 128 rows x 128 cols, grid (2, NG/128). ~50% of rows are masked ->
// staging BRANCHES around the global load (no fetch for masked rows) and
// stages zeros instead; MODE 0 epilogue skips stores for masked rows.
//   MODE 0: k = A@w_k + b_k  -> bf16 kmat[NG][256]   (unmasked rows only)
//   MODE 1: attnout_bf[n][c] = bf16( sum_k attn[n,h(c),k]*v[k][c] + b_v[c] )
// Wave w owns rows w*32..w*32+31 (= query blockIdx.y*4+w's neighbors, MODE 1).
// ---------------------------------------------------------------------------
template <int MODE>
__global__ __launch_bounds__(256) void k_gemm(const unsigned short* __restrict__ ln_x,
                                              const int* __restrict__ gidx,
                                              const int* __restrict__ mask_i,
                                              const unsigned short* __restrict__ w_kv_t,
                                              const float* __restrict__ bias,
                                              const float* __restrict__ attn,
                                              unsigned short* __restrict__ kout,
                                              unsigned short* __restrict__ attnout_bf) {
    __shared__ __align__(16) unsigned short As[128 * 32];   // row-major, stride 32
    __shared__ __align__(16) unsigned short Bt[128 * 40];   // col-major, stride 40
    __shared__ float attn_s[4 * 256];                       // MODE 1 only
    __shared__ int   msk_s[128];
    int tid = threadIdx.x;
    int w = tid >> 6, l = tid & 63;
    int rowbase = blockIdx.y * 128;
    int col0   = blockIdx.x * 128;
    int col0_w = col0 + (MODE ? 256 : 0);     // column base in w_kv_t space

    int r0 = tid >> 2, qt = tid & 3;
    int g0 = gidx[rowbase + r0];
    int m0 = mask_i[rowbase + r0];
    int g1 = gidx[rowbase + 64 + r0];
    int m1 = mask_i[rowbase + 64 + r0];
    const unsigned short* a0p = ln_x + (size_t)g0 * CH + qt * 8;
    const unsigned short* a1p = ln_x + (size_t)g1 * CH + qt * 8;
    if (tid < 128) msk_s[tid] = mask_i[rowbase + tid];

    if (MODE) {
        for (int i = tid; i < 1024; i += 256)
            attn_s[i] = attn[(size_t)blockIdx.y * 1024 + i];
    }

    f32x4 acc[2][8];
    #pragma unroll
    for (int mt = 0; mt < 2; mt++)
        #pragma unroll
        for (int nt = 0; nt < 8; nt++)
            acc[mt][nt] = (f32x4){0.f, 0.f, 0.f, 0.f};

    const int ml = l & 15, qd = l >> 4;
    // B chunk assignment: chunk id -> col id>>2, 16B quarter id&3
    const int bcol0 = tid >> 2, bsg = tid & 3;
    for (int kk = 0; kk < CH; kk += 32) {
        __syncthreads();
        uint4 v0 = {0u, 0u, 0u, 0u}, v1 = {0u, 0u, 0u, 0u};
        if (!m0) v0 = *(const uint4*)(a0p + kk);        // no fetch when masked
        if (!m1) v1 = *(const uint4*)(a1p + kk);
        *(uint4*)(As + tid * 8)        = v0;
        *(uint4*)(As + 2048 + tid * 8) = v1;
        {
            uint4 b0 = *(const uint4*)(w_kv_t + (size_t)(col0_w + bcol0) * CH + kk + bsg * 8);
            uint4 b1 = *(const uint4*)(w_kv_t + (size_t)(col0_w + 64 + bcol0) * CH + kk + bsg * 8);
            *(uint4*)(Bt + bcol0 * 40 + bsg * 8)        = b0;
            *(uint4*)(Bt + (64 + bcol0) * 40 + bsg * 8) = b1;
        }
        __syncthreads();
        bf16x8 a0 = *(const bf16x8*)(As + (w * 32 + ml) * 32 + qd * 8);
        bf16x8 a1 = *(const bf16x8*)(As + (w * 32 + 16 + ml) * 32 + qd * 8);
        #pragma unroll
        for (int nt = 0; nt < 8; nt++) {
            bf16x8 bb = *(const bf16x8*)(Bt + (nt * 16 + ml) * 40 + qd * 8);
            acc[0][nt] = __builtin_amdgcn_mfma_f32_16x16x32_bf16(a0, bb, acc[0][nt], 0, 0, 0);
            acc[1][nt] = __builtin_amdgcn_mfma_f32_16x16x32_bf16(a1, bb, acc[1][nt], 0, 0, 0);
        }
    }

    if (MODE == 0) {
        #pragma unroll
        for (int nt = 0; nt < 8; nt++) {
            int col = col0 + nt * 16 + ml;
            float bk = bias[col];
            #pragma unroll
            for (int mt = 0; mt < 2; mt++) {
                int rl = w * 32 + mt * 16 + qd * 4;
                #pragma unroll
                for (int i = 0; i < 4; i++)
                    if (!msk_s[rl + i])                  // skip masked-row stores
                        kout[(size_t)(rowbase + rl + i) * CH + col] = f2bf(acc[mt][nt][i] + bk);
            }
        }
    } else {
        #pragma unroll
        for (int nt = 0; nt < 8; nt++) {
            int col = col0 + nt * 16 + ml;
            int h = col >> 5;
            float ps = 0.f;
            #pragma unroll
            for (int mt = 0; mt < 2; mt++)
                #pragma unroll
                for (int i = 0; i < 4; i++) {
                    int kkk = mt * 16 + qd * 4 + i;
                    ps += attn_s[w * 256 + (h << 5) + kkk] * acc[mt][nt][i];
                }
            ps += __shfl_xor(ps, 16);
            ps += __shfl_xor(ps, 32);
            if (qd == 0)
                attnout_bf[(size_t)(blockIdx.y * 4 + w) * CH + col] = f2bf(ps + bias[col]);
        }
    }
}

// ---------------------------------------------------------------------------
// k_mm<KD,EPI>: plain row GEMM, A[8192][KD] bf16 @ Bt[cols][KD] bf16.
//   EPI 0: relu -> bf16 at ld FFD (FF1)   EPI 1: +bias+res -> fp32 (FF2)
//   EPI 2: +bias+res[qidx[row]] -> fp32 (proj)
// ---------------------------------------------------------------------------
template <int KD, int EPI>
__global__ __launch_bounds__(256) void k_mm(const unsigned short* __restrict__ A,
                                            const unsigned short* __restrict__ Bt_g,
                                            const float* __restrict__ bias,
                                            const float* __restrict__ res,
                                            const int* __restrict__ qidx,
                                            unsigned short* __restrict__ out_bf,
                                            float* __restrict__ out_f) {
    __shared__ __align__(16) unsigned short As[128 * 32];
    __shared__ __align__(16) unsigned short Bs[64 * 40];
    int tid = threadIdx.x;
    int w = tid >> 6, l = tid & 63;
    int rowbase = blockIdx.y * 128;
    int col0 = blockIdx.x * 64;
    int r0 = tid >> 2, qt = tid & 3;
    const unsigned short* a0p = A + (size_t)(rowbase + r0) * KD + qt * 8;
    const unsigned short* a1p = A + (size_t)(rowbase + 64 + r0) * KD + qt * 8;

    f32x4 acc[2][4];
    #pragma unroll
    for (int mt = 0; mt < 2; mt++)
        #pragma unroll
        for (int nt = 0; nt < 4; nt++)
            acc[mt][nt] = (f32x4){0.f, 0.f, 0.f, 0.f};

    const int ml = l & 15, qd = l >> 4;
    for (int kk = 0; kk < KD; kk += 32) {
        __syncthreads();
        uint4 v0 = *(const uint4*)(a0p + kk);
        uint4 v1 = *(const uint4*)(a1p + kk);
        *(uint4*)(As + tid * 8)        = v0;
        *(uint4*)(As + 2048 + tid * 8) = v1;
        {
            int cl = tid >> 2, sg = tid & 3;
            uint4 bv = *(const uint4*)(Bt_g + (size_t)(col0 + cl) * KD + kk + sg * 8);
            *(uint4*)(Bs + cl * 40 + sg * 8) = bv;
        }
        __syncthreads();
        bf16x8 a0 = *(const bf16x8*)(As + (w * 32 + ml) * 32 + qd * 8);
        bf16x8 a1 = *(const bf16x8*)(As + (w * 32 + 16 + ml) * 32 + qd * 8);
        #pragma unroll
        for (int nt = 0; nt < 4; nt++) {
            bf16x8 bb = *(const bf16x8*)(Bs + (nt * 16 + ml) * 40 + qd * 8);
            acc[0][nt] = __builtin_amdgcn_mfma_f32_16x16x32_bf16(a0, bb, acc[0][nt], 0, 0, 0);
            acc[1][nt] = __builtin_amdgcn_mfma_f32_16x16x32_bf16(a1, bb, acc[1][nt], 0, 0, 0);
        }
    }

    #pragma unroll
    for (int nt = 0; nt < 4; nt++) {
        int col = col0 + nt * 16 + ml;
        float bv = bias[col];
        #pragma unroll
        for (int mt = 0; mt < 2; mt++) {
            int rl = w * 32 + mt * 16 + qd * 4;
            #pragma unroll
            for (int i = 0; i < 4; i++) {
                int row = rowbase + rl + i;
                float v = acc[mt][nt][i] + bv;
                if (EPI == 0) {
                    out_bf[(size_t)row * FFD + col] = f2bf(fmaxf(v, 0.f));
                } else if (EPI == 1) {
                    out_f[(size_t)row * CH + col] = v + res[(size_t)row * CH + col];
                } else {
                    int qi = qidx[row];
                    out_f[(size_t)row * CH + col] = v + res[(size_t)qi * CH + col];
                }
            }
        }
    }
}

// ---------------------------------------------------------------------------
// k_attn: logits -> softmax. Branch-skips the kv load for masked entries.
// ---------------------------------------------------------------------------
__global__ __launch_bounds__(256) void k_attn(const float* __restrict__ qbuf,
                                              const float* __restrict__ qp,
                                              const unsigned short* __restrict__ kmat,
                                              const int* __restrict__ mask_i,
                                              const int* __restrict__ rel_x,
                                              const int* __restrict__ rel_y,
                                              const int* __restrict__ rel_z,
                                              const float* __restrict__ pos_kx,
                                              const float* __restrict__ pos_ky,
                                              const float* __restrict__ pos_kz,
                                              float* __restrict__ attn) {
    __shared__ float pos_s[9472];     // [x:3840][y:3840][z:1792]
    __shared__ float q_s[1024];
    __shared__ float qp_s[4 * QPN];
    int tid = threadIdx.x;
    int qb = blockIdx.x * 4;
    for (int i = tid; i < 3840; i += 256) pos_s[i] = pos_kx[i];
    for (int i = tid; i < 3840; i += 256) pos_s[3840 + i] = pos_ky[i];
    for (int i = tid; i < 1792; i += 256) pos_s[7680 + i] = pos_kz[i];
    for (int i = tid; i < 1024; i += 256) q_s[i] = qbuf[(size_t)qb * CH + i];
    for (int i = tid; i < 4 * QPN; i += 256) qp_s[i] = qp[(size_t)qb * QPN + i];
    __syncthreads();
    int h = tid >> 5, k = tid & 31;
    const float scale = 0.17677669529663687f;   // 32^-0.5
    for (int qq = 0; qq < 4; qq++) {
        int n = qb + qq;
        int gi = n * KN + k;
        int mk = mask_i[gi];
        float lg;
        if (mk) {
            lg = -1e9f;
        } else {
            int rx = rel_x[gi], ry = rel_y[gi], rz = rel_z[gi];
            const uint4* kp = (const uint4*)(kmat + (size_t)gi * CH + h * DHD);
            float kv[32];
            #pragma unroll
            for (int j = 0; j < 4; j++) {
                uint4 u = kp[j];
                kv[j * 8 + 0] = bf2f((unsigned short)(u.x & 0xFFFF));
                kv[j * 8 + 1] = bf2f((unsigned short)(u.x >> 16));
                kv[j * 8 + 2] = bf2f((unsigned short)(u.y & 0xFFFF));
                kv[j * 8 + 3] = bf2f((unsigned short)(u.y >> 16));
                kv[j * 8 + 4] = bf2f((unsigned short)(u.z & 0xFFFF));
                kv[j * 8 + 5] = bf2f((unsigned short)(u.z >> 16));
                kv[j * 8 + 6] = bf2f((unsigned short)(u.w & 0xFFFF));
                kv[j * 8 + 7] = bf2f((unsigned short)(u.w >> 16));
            }
            float s1 = 0.f, s2 = 0.f;
            const float* qrow = q_s + qq * CH + h * DHD;
            const float* px = pos_s + h * 480 + rx;
            const float* py = pos_s + 3840 + h * 480 + ry;
            const float* pz = pos_s + 7680 + h * 224 + rz;
            #pragma unroll
            for (int d = 0; d < 32; d++) {
                s1 += kv[d] * qrow[d];
                s2 += kv[d] * (px[d * 15] + py[d * 15] + pz[d * 7]);
            }
            lg = s1 * scale + s2
               + qp_s[qq * QPN + h * QPW + rx]
               + qp_s[qq * QPN + h * QPW + 15 + ry]
               + qp_s[qq * QPN + h * QPW + 30 + rz];
        }
        float mx = lg;
        #pragma unroll
        for (int off = 1; off <= 16; off <<= 1) mx = fmaxf(mx, __shfl_xor(mx, off));
        float e = __expf(lg - mx);
        float sm = e;
        #pragma unroll
        for (int off = 1; off <= 16; off <<= 1) sm += __shfl_xor(sm, off);
        attn[(size_t)n * 256 + tid] = e / sm;
    }
}

// ---------------------------------------------------------------------------
extern "C" void kernel_launch(void* const* d_in, const int* in_sizes, int n_in,
                              void* d_out, int out_size, void* d_ws, size_t ws_size,
                              hipStream_t stream) {
    (void)in_sizes; (void)n_in; (void)out_size; (void)ws_size;
    const float* vox    = (const float*)d_in[0];
    const float* coords = (const float*)d_in[1];
    const int*   qidx   = (const int*)d_in[2];
    const int*   gidx   = (const int*)d_in[3];
    const void*  mraw   = d_in[4];
    const int*   rel_x  = (const int*)d_in[5];
    const int*   rel_y  = (const int*)d_in[6];
    const int*   rel_z  = (const int*)d_in[7];
    const float* w_pos  = (const float*)d_in[8];
    const float* b_pos  = (const float*)d_in[9];
    const float* w_q    = (const float*)d_in[10];
    const float* b_q    = (const float*)d_in[11];
    const float* w_k    = (const float*)d_in[12];
    const float* b_k    = (const float*)d_in[13];
    const float* w_v    = (const float*)d_in[14];
    const float* b_v    = (const float*)d_in[15];
    const float* w_proj = (const float*)d_in[16];
    const float* b_proj = (const float*)d_in[17];
    const float* ln1_g  = (const float*)d_in[18];
    const float* ln1_b  = (const float*)d_in[19];
    const float* ln2_g  = (const float*)d_in[20];
    const float* ln2_b  = (const float*)d_in[21];
    const float* w_ff1  = (const float*)d_in[22];
    const float* b_ff1  = (const float*)d_in[23];
    const float* w_ff2  = (const float*)d_in[24];
    const float* b_ff2  = (const float*)d_in[25];
    const float* pos_qx = (const float*)d_in[26];
    const float* pos_qy = (const float*)d_in[27];
    const float* pos_qz = (const float*)d_in[28];
    const float* pos_kx = (const float*)d_in[29];
    const float* pos_ky = (const float*)d_in[30];
    const float* pos_kz = (const float*)d_in[31];

    // workspace carve (~240 MB total)
    char* p = (char*)d_ws;
    auto take = [&](size_t n) { char* r = p; p += (n + 255) & ~(size_t)255; return r; };
    unsigned short* ln_x    = (unsigned short*)take((size_t)MV * CH * 2);   // 51.2 MB
    unsigned short* w_kv_t  = (unsigned short*)take((size_t)512 * 256 * 2);
    unsigned short* w1_t    = (unsigned short*)take((size_t)512 * 256 * 2);
    unsigned short* w2_t    = (unsigned short*)take((size_t)256 * 512 * 2);
    unsigned short* wp_t    = (unsigned short*)take((size_t)256 * 256 * 2);
    int*            flag    = (int*)take(256);
    int*            mask_i  = (int*)take((size_t)NG * 4);                   // 1.05 MB
    float*          qbuf    = (float*)take((size_t)NQ * CH * 4);            // 8.4 MB
    float*          qp      = (float*)take((size_t)NQ * QPN * 4);           // 9.7 MB
    unsigned short* kmat    = (unsigned short*)take((size_t)NG * CH * 2);   // 134 MB
    float*          attn    = (float*)take((size_t)NQ * 256 * 4);           // 8.4 MB
    unsigned short* attnln  = (unsigned short*)take((size_t)NQ * CH * 2);   // 4.2 MB
    float*          actbuf  = (float*)take((size_t)NQ * CH * 4);            // 8.4 MB
    unsigned short* actln   = (unsigned short*)take((size_t)NQ * CH * 2);   // 4.2 MB
    unsigned short* hbuf    = (unsigned short*)take((size_t)NQ * FFD * 2);  // 8.4 MB

    hipLaunchKernelGGL(k_detect_mask, dim3(1), dim3(256), 0, stream,
                       (const unsigned char*)mraw, flag);
    hipLaunchKernelGGL(k_prep, dim3(NG / 256), dim3(256), 0, stream,
                       w_k, w_v, w_ff1, w_ff2, w_proj, mraw, flag,
                       w_kv_t, w1_t, w2_t, wp_t, mask_i);
    hipLaunchKernelGGL(k_ln, dim3(MV / 4 + 1), dim3(256), 0, stream,
                       vox, ln1_g, ln1_b, ln_x, MV);
    hipLaunchKernelGGL(k_q, dim3(NQ / 8), dim3(256), 0, stream,
                       ln_x, coords, qidx, w_pos, b_pos, w_q, b_q,
                       pos_qx, pos_qy, pos_qz, qbuf, qp);
    hipLaunchKernelGGL(HIP_KERNEL_NAME(k_gemm<0>), dim3(2, NG / 128), dim3(256), 0, stream,
                       ln_x, gidx, mask_i, w_kv_t, b_k, (const float*)nullptr,
                       kmat, (unsigned short*)nullptr);
    hipLaunchKernelGGL(k_attn, dim3(NQ / 4), dim3(256), 0, stream,
                       qbuf, qp, kmat, mask_i, rel_x, rel_y, rel_z,
                       pos_kx, pos_ky, pos_kz, attn);
    hipLaunchKernelGGL(HIP_KERNEL_NAME(k_gemm<1>), dim3(2, NG / 128), dim3(256), 0, stream,
                       ln_x, gidx, mask_i, w_kv_t, b_v, attn,
                       (unsigned short*)nullptr, attnln);
    // proj: act = attn_bf16 @ wp_t + b_proj + vox[qidx]
    hipLaunchKernelGGL(HIP_KERNEL_NAME(k_mm<256, 2>), dim3(4, NQ / 128), dim3(256), 0, stream,
                       attnln, wp_t, b_proj, vox, qidx,
                       (unsigned short*)nullptr, actbuf);
    hipLaunchKernelGGL(k_ln, dim3(NQ / 4), dim3(256), 0, stream,
                       actbuf, ln2_g, ln2_b, actln, NQ);
    // FF1: h = relu(actln @ w1_t + b_ff1)
    hipLaunchKernelGGL(HIP_KERNEL_NAME(k_mm<256, 0>), dim3(8, NQ / 128), dim3(256), 0, stream,
                       actln, w1_t, b_ff1, (const float*)nullptr, (const int*)nullptr,
                       hbuf, (float*)nullptr);
    // FF2: out = h @ w2_t + b_ff2 + act
    hipLaunchKernelGGL(HIP_KERNEL_NAME(k_mm<512, 1>), dim3(4, NQ / 128), dim3(256), 0, stream,
                       hbuf, w2_t, b_ff2, actbuf, (const int*)nullptr,
                       (unsigned short*)nullptr, (float*)d_out);
}

// Round 4
// 564.144 us; speedup vs baseline: 1.0228x; 1.0228x over previous
//
#include <hip/hip_runtime.h>
#include <hip/hip_bf16.h>
#include <math.h>

// Problem constants (fixed by the reference)
#define MV   100000          // voxels
#define NQ   8192            // queries
#define KN   32              // neighbors per query
#define CH   256             // channels
#define NH   8               // heads
#define DHD  32              // head dim
#define FFD  512             // FF hidden
#define NG   (NQ*KN)         // 262144 gathered rows
#define QPW  37              // 15+15+7 rel-pos columns per head (q-side)
#define QPN  (NH*QPW)        // 296
#define ASTR 40              // padded LDS row stride (shorts): (20*ml+4*qd)%32 -> 2-way, free

typedef __bf16 bf16x8 __attribute__((ext_vector_type(8)));
typedef float  f32x4  __attribute__((ext_vector_type(4)));

__device__ __forceinline__ float bf2f(unsigned short u) {
    return __uint_as_float(((unsigned int)u) << 16);
}
__device__ __forceinline__ unsigned short f2bf(float f) {
    unsigned int x = __float_as_uint(f);
    unsigned int r = x + 0x7FFFu + ((x >> 16) & 1u);   // RNE
    return (unsigned short)(r >> 16);
}

// ---------------------------------------------------------------------------
// k_detect_mask: gather_mask may ship as int32 (0/1) or raw 1-byte bools.
// 64 blocks, each ORs its 4 KB slice into flags[blockIdx]. (Single-block
// version was a serial 1 MB scan = pure latency overhead.)
// ---------------------------------------------------------------------------
__global__ __launch_bounds__(256) void k_detect_mask(const unsigned char* __restrict__ raw,
                                                     int* __restrict__ flags) {
    __shared__ int any;
    if (threadIdx.x == 0) any = 0;
    __syncthreads();
    const uint4* p = (const uint4*)raw;             // NG bytes = 16384 uint4
    int i = blockIdx.x * 256 + threadIdx.x;
    uint4 v = p[i];
    if ((v.x | v.y | v.z | v.w) & 0xFFFFFF00u) any = 1;
    __syncthreads();
    if (threadIdx.x == 0) flags[blockIdx.x] = any;
}

// ---------------------------------------------------------------------------
// k_prep: int mask (layout-adaptive) + bf16 col-major (B-layout) weights.
// ---------------------------------------------------------------------------
__global__ __launch_bounds__(256) void k_prep(const float* __restrict__ w_k,
                                              const float* __restrict__ w_v,
                                              const float* __restrict__ w_ff1,
                                              const float* __restrict__ w_ff2,
                                              const float* __restrict__ w_proj,
                                              const void* __restrict__ mask_raw,
                                              const int* __restrict__ flags,
                                              unsigned short* __restrict__ w_kv_t,
                                              unsigned short* __restrict__ w1_t,
                                              unsigned short* __restrict__ w2_t,
                                              unsigned short* __restrict__ wp_t,
                                              int* __restrict__ mask_i) {
    __shared__ int bl;
    if (threadIdx.x == 0) {
        int a = 0;
        #pragma unroll 8
        for (int i = 0; i < 64; i++) a |= flags[i];
        bl = a;
    }
    __syncthreads();
    int byteLayout = bl;
    int idx = blockIdx.x * 256 + threadIdx.x;       // grid 1024 -> 262144
    if (idx < NG) {
        int mv = byteLayout ? (int)((const unsigned char*)mask_raw)[idx]
                            : ((const int*)mask_raw)[idx];
        mask_i[idx] = (mv != 0) ? 1 : 0;
    }
    if (idx < 512 * 256) {
        int col = idx >> 8, j = idx & 255;
        float v = (col < 256) ? w_k[j * 256 + col] : w_v[j * 256 + (col - 256)];
        w_kv_t[idx] = f2bf(v);
    }
    if (idx < 512 * 256) {
        int n = idx >> 8, k = idx & 255;
        w1_t[idx] = f2bf(w_ff1[k * FFD + n]);
    }
    if (idx < 256 * 512) {
        int n = idx >> 9, k = idx & 511;
        w2_t[idx] = f2bf(w_ff2[k * CH + n]);
    }
    if (idx < 256 * 256) {
        int n = idx >> 8, k = idx & 255;
        wp_t[idx] = f2bf(w_proj[k * CH + n]);
    }
}

// ---------------------------------------------------------------------------
// k_ln: LayerNorm rows of x[nrows][256] -> bf16. One wave per row.
// ---------------------------------------------------------------------------
__global__ __launch_bounds__(256) void k_ln(const float* __restrict__ x,
                                            const float* __restrict__ g,
                                            const float* __restrict__ b,
                                            unsigned short* __restrict__ o,
                                            int nrows) {
    int wid = threadIdx.x >> 6, lane = threadIdx.x & 63;
    int row = blockIdx.x * 4 + wid;
    if (row >= nrows) return;
    const float4 v = *(const float4*)(x + (size_t)row * CH + lane * 4);
    float s  = v.x + v.y + v.z + v.w;
    float sq = v.x * v.x + v.y * v.y + v.z * v.z + v.w * v.w;
    #pragma unroll
    for (int off = 1; off < 64; off <<= 1) {
        s  += __shfl_xor(s,  off);
        sq += __shfl_xor(sq, off);
    }
    float mu  = s * (1.f / CH);
    float var = sq * (1.f / CH) - mu * mu;
    float rs  = rsqrtf(var + 1e-5f);
    float4 gv = *(const float4*)(g + lane * 4);
    float4 bv = *(const float4*)(b + lane * 4);
    ushort4 ov;
    ov.x = f2bf((v.x - mu) * rs * gv.x + bv.x);
    ov.y = f2bf((v.y - mu) * rs * gv.y + bv.y);
    ov.z = f2bf((v.z - mu) * rs * gv.z + bv.z);
    ov.w = f2bf((v.w - mu) * rs * gv.w + bv.w);
    *(ushort4*)(o + (size_t)row * CH + lane * 4) = ov;
}

// ---------------------------------------------------------------------------
// k_q: q = (ln_x[qi]+relu(pos))@w_q + b_q (fp32) + q-side rel tables qp.
// ---------------------------------------------------------------------------
__global__ __launch_bounds__(256) void k_q(const unsigned short* __restrict__ ln_x,
                                           const float* __restrict__ coords,
                                           const int* __restrict__ qidx,
                                           const float* __restrict__ w_pos,
                                           const float* __restrict__ b_pos,
                                           const float* __restrict__ w_q,
                                           const float* __restrict__ b_q,
                                           const float* __restrict__ pos_qx,
                                           const float* __restrict__ pos_qy,
                                           const float* __restrict__ pos_qz,
                                           float* __restrict__ qout,
                                           float* __restrict__ qp) {
    __shared__ float qin_s[8 * CH];
    __shared__ float q_s[8 * CH];
    int c = threadIdx.x;
    int nb = blockIdx.x * 8;
    float wp0 = w_pos[c], wp1 = w_pos[CH + c], wp2 = w_pos[2 * CH + c], bp = b_pos[c];
    #pragma unroll
    for (int qq = 0; qq < 8; qq++) {
        int n = nb + qq;
        float p = bp + coords[n * 3] * wp0 + coords[n * 3 + 1] * wp1 + coords[n * 3 + 2] * wp2;
        p = fmaxf(p, 0.f);
        int qi = qidx[n];
        qin_s[qq * CH + c] = bf2f(ln_x[(size_t)qi * CH + c]) + p;
    }
    __syncthreads();
    float acc[8];
    float bq = b_q[c];
    #pragma unroll
    for (int qq = 0; qq < 8; qq++) acc[qq] = bq;
    #pragma unroll 4
    for (int j = 0; j < CH; j++) {
        float w = w_q[j * CH + c];
        #pragma unroll
        for (int qq = 0; qq < 8; qq++) acc[qq] += qin_s[qq * CH + j] * w;
    }
    #pragma unroll
    for (int qq = 0; qq < 8; qq++) {
        qout[(size_t)(nb + qq) * CH + c] = acc[qq];
        q_s[qq * CH + c] = acc[qq];
    }
    __syncthreads();
    for (int t = threadIdx.x; t < 8 * QPN; t += 256) {
        int qq = t / QPN, u = t % QPN;
        int h = u / QPW, r = u % QPW;
        const float* tab; int rr, R;
        if (r < 15)      { tab = pos_qx; rr = r;      R = 15; }
        else if (r < 30) { tab = pos_qy; rr = r - 15; R = 15; }
        else             { tab = pos_qz; rr = r - 30; R = 7;  }
        float a = 0.f;
        const float* qrow = q_s + qq * CH + h * DHD;
        #pragma unroll
        for (int d = 0; d < DHD; d++) a += qrow[d] * tab[(h * DHD + d) * R + rr];
        qp[(size_t)(nb + qq) * QPN + u] = a;
    }
}

// ---------------------------------------------------------------------------
// k_gemm<MODE>: gathered-row GEMM over the 262144 (n,k) rows.
// Tile 128x64 (R2-proven), grid (4, NG/128). Masked rows (~50%): staging
// branches around the load (no fetch) and stages zeros; MODE 0 skips their
// stores. As/Bt stride 40 shorts -> 2-way banks (free) on reads AND writes.
//   MODE 0: k = A@w_k + b_k  -> bf16 kmat[NG][256]   (unmasked rows only)
//   MODE 1: attnout_bf[n][c] = bf16( sum_k attn[n,h(c),k]*v[k][c] + b_v[c] )
// ---------------------------------------------------------------------------
template <int MODE>
__global__ __launch_bounds__(256) void k_gemm(const unsigned short* __restrict__ ln_x,
                                              const int* __restrict__ gidx,
                                              const int* __restrict__ mask_i,
                                              const unsigned short* __restrict__ w_kv_t,
                                              const float* __restrict__ bias,
                                              const float* __restrict__ attn,
                                              unsigned short* __restrict__ kout,
                                              unsigned short* __restrict__ attnout_bf) {
    __shared__ __align__(16) unsigned short As[128 * ASTR];
    __shared__ __align__(16) unsigned short Bt[64 * ASTR];
    __shared__ float attn_s[4 * 256];                       // MODE 1 only
    __shared__ int   msk_s[128];
    int tid = threadIdx.x;
    int w = tid >> 6, l = tid & 63;
    int rowbase = blockIdx.y * 128;
    int col0   = blockIdx.x * 64;
    int col0_w = col0 + (MODE ? 256 : 0);     // column base in w_kv_t space

    int r0 = tid >> 2, qt = tid & 3;
    int g0 = gidx[rowbase + r0];
    int m0 = mask_i[rowbase + r0];
    int g1 = gidx[rowbase + 64 + r0];
    int m1 = mask_i[rowbase + 64 + r0];
    const unsigned short* a0p = ln_x + (size_t)g0 * CH + qt * 8;
    const unsigned short* a1p = ln_x + (size_t)g1 * CH + qt * 8;
    if (tid < 128) msk_s[tid] = mask_i[rowbase + tid];

    if (MODE) {
        for (int i = tid; i < 1024; i += 256)
            attn_s[i] = attn[(size_t)blockIdx.y * 1024 + i];
    }

    f32x4 acc[2][4];
    #pragma unroll
    for (int mt = 0; mt < 2; mt++)
        #pragma unroll
        for (int nt = 0; nt < 4; nt++)
            acc[mt][nt] = (f32x4){0.f, 0.f, 0.f, 0.f};

    const int ml = l & 15, qd = l >> 4;
    for (int kk = 0; kk < CH; kk += 32) {
        __syncthreads();
        uint4 v0 = {0u, 0u, 0u, 0u}, v1 = {0u, 0u, 0u, 0u};
        if (!m0) v0 = *(const uint4*)(a0p + kk);        // no fetch when masked
        if (!m1) v1 = *(const uint4*)(a1p + kk);
        *(uint4*)(As + r0 * ASTR + qt * 8)        = v0;
        *(uint4*)(As + (64 + r0) * ASTR + qt * 8) = v1;
        {
            uint4 bv = *(const uint4*)(w_kv_t + (size_t)(col0_w + r0) * CH + kk + qt * 8);
            *(uint4*)(Bt + r0 * ASTR + qt * 8) = bv;
        }
        __syncthreads();
        bf16x8 a0 = *(const bf16x8*)(As + (w * 32 + ml) * ASTR + qd * 8);
        bf16x8 a1 = *(const bf16x8*)(As + (w * 32 + 16 + ml) * ASTR + qd * 8);
        #pragma unroll
        for (int nt = 0; nt < 4; nt++) {
            bf16x8 bb = *(const bf16x8*)(Bt + (nt * 16 + ml) * ASTR + qd * 8);
            acc[0][nt] = __builtin_amdgcn_mfma_f32_16x16x32_bf16(a0, bb, acc[0][nt], 0, 0, 0);
            acc[1][nt] = __builtin_amdgcn_mfma_f32_16x16x32_bf16(a1, bb, acc[1][nt], 0, 0, 0);
        }
    }

    if (MODE == 0) {
        #pragma unroll
        for (int nt = 0; nt < 4; nt++) {
            int col = col0 + nt * 16 + ml;
            float bk = bias[col];
            #pragma unroll
            for (int mt = 0; mt < 2; mt++) {
                int rl = w * 32 + mt * 16 + qd * 4;
                #pragma unroll
                for (int i = 0; i < 4; i++)
                    if (!msk_s[rl + i])                  // skip masked-row stores
                        kout[(size_t)(rowbase + rl + i) * CH + col] = f2bf(acc[mt][nt][i] + bk);
            }
        }
    } else {
        // wave w == query blockIdx.y*4 + w; its 32 rows are that query's k's
        #pragma unroll
        for (int nt = 0; nt < 4; nt++) {
            int col = col0 + nt * 16 + ml;
            int h = col >> 5;
            float ps = 0.f;
            #pragma unroll
            for (int mt = 0; mt < 2; mt++)
                #pragma unroll
                for (int i = 0; i < 4; i++) {
                    int kkk = mt * 16 + qd * 4 + i;
                    ps += attn_s[w * 256 + (h << 5) + kkk] * acc[mt][nt][i];
                }
            ps += __shfl_xor(ps, 16);
            ps += __shfl_xor(ps, 32);
            if (qd == 0)
                attnout_bf[(size_t)(blockIdx.y * 4 + w) * CH + col] = f2bf(ps + bias[col]);
        }
    }
}

// ---------------------------------------------------------------------------
// k_mm<KD,EPI>: plain row GEMM, A[8192][KD] bf16 @ Bt[cols][KD] bf16.
//   EPI 0: relu -> bf16 at ld FFD (FF1)   EPI 1: +bias+res -> fp32 (FF2)
//   EPI 2: +bias+res[qidx[row]] -> fp32 (proj)
// ---------------------------------------------------------------------------
template <int KD, int EPI>
__global__ __launch_bounds__(256) void k_mm(const unsigned short* __restrict__ A,
                                            const unsigned short* __restrict__ Bt_g,
                                            const float* __restrict__ bias,
                                            const float* __restrict__ res,
                                            const int* __restrict__ qidx,
                                            unsigned short* __restrict__ out_bf,
                                            float* __restrict__ out_f) {
    __shared__ __align__(16) unsigned short As[128 * ASTR];
    __shared__ __align__(16) unsigned short Bs[64 * ASTR];
    int tid = threadIdx.x;
    int w = tid >> 6, l = tid & 63;
    int rowbase = blockIdx.y * 128;
    int col0 = blockIdx.x * 64;
    int r0 = tid >> 2, qt = tid & 3;
    const unsigned short* a0p = A + (size_t)(rowbase + r0) * KD + qt * 8;
    const unsigned short* a1p = A + (size_t)(rowbase + 64 + r0) * KD + qt * 8;

    f32x4 acc[2][4];
    #pragma unroll
    for (int mt = 0; mt < 2; mt++)
        #pragma unroll
        for (int nt = 0; nt < 4; nt++)
            acc[mt][nt] = (f32x4){0.f, 0.f, 0.f, 0.f};

    const int ml = l & 15, qd = l >> 4;
    for (int kk = 0; kk < KD; kk += 32) {
        __syncthreads();
        uint4 v0 = *(const uint4*)(a0p + kk);
        uint4 v1 = *(const uint4*)(a1p + kk);
        *(uint4*)(As + r0 * ASTR + qt * 8)        = v0;
        *(uint4*)(As + (64 + r0) * ASTR + qt * 8) = v1;
        {
            uint4 bv = *(const uint4*)(Bt_g + (size_t)(col0 + r0) * KD + kk + qt * 8);
            *(uint4*)(Bs + r0 * ASTR + qt * 8) = bv;
        }
        __syncthreads();
        bf16x8 a0 = *(const bf16x8*)(As + (w * 32 + ml) * ASTR + qd * 8);
        bf16x8 a1 = *(const bf16x8*)(As + (w * 32 + 16 + ml) * ASTR + qd * 8);
        #pragma unroll
        for (int nt = 0; nt < 4; nt++) {
            bf16x8 bb = *(const bf16x8*)(Bs + (nt * 16 + ml) * ASTR + qd * 8);
            acc[0][nt] = __builtin_amdgcn_mfma_f32_16x16x32_bf16(a0, bb, acc[0][nt], 0, 0, 0);
            acc[1][nt] = __builtin_amdgcn_mfma_f32_16x16x32_bf16(a1, bb, acc[1][nt], 0, 0, 0);
        }
    }

    #pragma unroll
    for (int nt = 0; nt < 4; nt++) {
        int col = col0 + nt * 16 + ml;
        float bv = bias[col];
        #pragma unroll
        for (int mt = 0; mt < 2; mt++) {
            int rl = w * 32 + mt * 16 + qd * 4;
            #pragma unroll
            for (int i = 0; i < 4; i++) {
                int row = rowbase + rl + i;
                float v = acc[mt][nt][i] + bv;
                if (EPI == 0) {
                    out_bf[(size_t)row * FFD + col] = f2bf(fmaxf(v, 0.f));
                } else if (EPI == 1) {
                    out_f[(size_t)row * CH + col] = v + res[(size_t)row * CH + col];
                } else {
                    int qi = qidx[row];
                    out_f[(size_t)row * CH + col] = v + res[(size_t)qi * CH + col];
                }
            }
        }
    }
}

// ---------------------------------------------------------------------------
// k_attn: logits -> softmax. Branch-skips kv load for masked entries; masked
// lanes contribute e=0 exactly, all-masked queries emit attn=0 (epilogue's
// +b_v then reproduces the reference output).
// ---------------------------------------------------------------------------
__global__ __launch_bounds__(256) void k_attn(const float* __restrict__ qbuf,
                                              const float* __restrict__ qp,
                                              const unsigned short* __restrict__ kmat,
                                              const int* __restrict__ mask_i,
                                              const int* __restrict__ rel_x,
                                              const int* __restrict__ rel_y,
                                              const int* __restrict__ rel_z,
                                              const float* __restrict__ pos_kx,
                                              const float* __restrict__ pos_ky,
                                              const float* __restrict__ pos_kz,
                                              float* __restrict__ attn) {
    __shared__ float pos_s[9472];     // [x:3840][y:3840][z:1792]
    __shared__ float q_s[1024];
    __shared__ float qp_s[4 * QPN];
    int tid = threadIdx.x;
    int qb = blockIdx.x * 4;
    for (int i = tid; i < 3840; i += 256) pos_s[i] = pos_kx[i];
    for (int i = tid; i < 3840; i += 256) pos_s[3840 + i] = pos_ky[i];
    for (int i = tid; i < 1792; i += 256) pos_s[7680 + i] = pos_kz[i];
    for (int i = tid; i < 1024; i += 256) q_s[i] = qbuf[(size_t)qb * CH + i];
    for (int i = tid; i < 4 * QPN; i += 256) qp_s[i] = qp[(size_t)qb * QPN + i];
    __syncthreads();
    int h = tid >> 5, k = tid & 31;
    const float scale = 0.17677669529663687f;   // 32^-0.5
    for (int qq = 0; qq < 4; qq++) {
        int n = qb + qq;
        int gi = n * KN + k;
        int mk = mask_i[gi];
        float lg = -1e9f;
        if (!mk) {
            int rx = rel_x[gi], ry = rel_y[gi], rz = rel_z[gi];
            const uint4* kp = (const uint4*)(kmat + (size_t)gi * CH + h * DHD);
            float kv[32];
            #pragma unroll
            for (int j = 0; j < 4; j++) {
                uint4 u = kp[j];
                kv[j * 8 + 0] = bf2f((unsigned short)(u.x & 0xFFFF));
                kv[j * 8 + 1] = bf2f((unsigned short)(u.x >> 16));
                kv[j * 8 + 2] = bf2f((unsigned short)(u.y & 0xFFFF));
                kv[j * 8 + 3] = bf2f((unsigned short)(u.y >> 16));
                kv[j * 8 + 4] = bf2f((unsigned short)(u.z & 0xFFFF));
                kv[j * 8 + 5] = bf2f((unsigned short)(u.z >> 16));
                kv[j * 8 + 6] = bf2f((unsigned short)(u.w & 0xFFFF));
                kv[j * 8 + 7] = bf2f((unsigned short)(u.w >> 16));
            }
            float s1 = 0.f, s2 = 0.f;
            const float* qrow = q_s + qq * CH + h * DHD;
            const float* px = pos_s + h * 480 + rx;
            const float* py = pos_s + 3840 + h * 480 + ry;
            const float* pz = pos_s + 7680 + h * 224 + rz;
            #pragma unroll
            for (int d = 0; d < 32; d++) {
                s1 += kv[d] * qrow[d];
                s2 += kv[d] * (px[d * 15] + py[d * 15] + pz[d * 7]);
            }
            lg = s1 * scale + s2
               + qp_s[qq * QPN + h * QPW + rx]
               + qp_s[qq * QPN + h * QPW + 15 + ry]
               + qp_s[qq * QPN + h * QPW + 30 + rz];
        }
        float mx = lg;
        #pragma unroll
        for (int off = 1; off <= 16; off <<= 1) mx = fmaxf(mx, __shfl_xor(mx, off));
        float e = mk ? 0.f : __expf(lg - mx);
        float sm = e;
        #pragma unroll
        for (int off = 1; off <= 16; off <<= 1) sm += __shfl_xor(sm, off);
        attn[(size_t)n * 256 + tid] = (sm > 0.f) ? e / sm : 0.f;
    }
}

// ---------------------------------------------------------------------------
extern "C" void kernel_launch(void* const* d_in, const int* in_sizes, int n_in,
                              void* d_out, int out_size, void* d_ws, size_t ws_size,
                              hipStream_t stream) {
    (void)in_sizes; (void)n_in; (void)out_size; (void)ws_size;
    const float* vox    = (const float*)d_in[0];
    const float* coords = (const float*)d_in[1];
    const int*   qidx   = (const int*)d_in[2];
    const int*   gidx   = (const int*)d_in[3];
    const void*  mraw   = d_in[4];
    const int*   rel_x  = (const int*)d_in[5];
    const int*   rel_y  = (const int*)d_in[6];
    const int*   rel_z  = (const int*)d_in[7];
    const float* w_pos  = (const float*)d_in[8];
    const float* b_pos  = (const float*)d_in[9];
    const float* w_q    = (const float*)d_in[10];
    const float* b_q    = (const float*)d_in[11];
    const float* w_k    = (const float*)d_in[12];
    const float* b_k    = (const float*)d_in[13];
    const float* w_v    = (const float*)d_in[14];
    const float* b_v    = (const float*)d_in[15];
    const float* w_proj = (const float*)d_in[16];
    const float* b_proj = (const float*)d_in[17];
    const float* ln1_g  = (const float*)d_in[18];
    const float* ln1_b  = (const float*)d_in[19];
    const float* ln2_g  = (const float*)d_in[20];
    const float* ln2_b  = (const float*)d_in[21];
    const float* w_ff1  = (const float*)d_in[22];
    const float* b_ff1  = (const float*)d_in[23];
    const float* w_ff2  = (const float*)d_in[24];
    const float* b_ff2  = (const float*)d_in[25];
    const float* pos_qx = (const float*)d_in[26];
    const float* pos_qy = (const float*)d_in[27];
    const float* pos_qz = (const float*)d_in[28];
    const float* pos_kx = (const float*)d_in[29];
    const float* pos_ky = (const float*)d_in[30];
    const float* pos_kz = (const float*)d_in[31];

    // workspace carve (~240 MB total)
    char* p = (char*)d_ws;
    auto take = [&](size_t n) { char* r = p; p += (n + 255) & ~(size_t)255; return r; };
    unsigned short* ln_x    = (unsigned short*)take((size_t)MV * CH * 2);   // 51.2 MB
    unsigned short* w_kv_t  = (unsigned short*)take((size_t)512 * 256 * 2);
    unsigned short* w1_t    = (unsigned short*)take((size_t)512 * 256 * 2);
    unsigned short* w2_t    = (unsigned short*)take((size_t)256 * 512 * 2);
    unsigned short* wp_t    = (unsigned short*)take((size_t)256 * 256 * 2);
    int*            flags   = (int*)take(64 * 4);
    int*            mask_i  = (int*)take((size_t)NG * 4);                   // 1.05 MB
    float*          qbuf    = (float*)take((size_t)NQ * CH * 4);            // 8.4 MB
    float*          qp      = (float*)take((size_t)NQ * QPN * 4);           // 9.7 MB
    unsigned short* kmat    = (unsigned short*)take((size_t)NG * CH * 2);   // 134 MB
    float*          attn    = (float*)take((size_t)NQ * 256 * 4);           // 8.4 MB
    unsigned short* attnln  = (unsigned short*)take((size_t)NQ * CH * 2);   // 4.2 MB
    float*          actbuf  = (float*)take((size_t)NQ * CH * 4);            // 8.4 MB
    unsigned short* actln   = (unsigned short*)take((size_t)NQ * CH * 2);   // 4.2 MB
    unsigned short* hbuf    = (unsigned short*)take((size_t)NQ * FFD * 2);  // 8.4 MB

    hipLaunchKernelGGL(k_detect_mask, dim3(64), dim3(256), 0, stream,
                       (const unsigned char*)mraw, flags);
    hipLaunchKernelGGL(k_prep, dim3(NG / 256), dim3(256), 0, stream,
                       w_k, w_v, w_ff1, w_ff2, w_proj, mraw, flags,
                       w_kv_t, w1_t, w2_t, wp_t, mask_i);
    hipLaunchKernelGGL(k_ln, dim3(MV / 4 + 1), dim3(256), 0, stream,
                       vox, ln1_g, ln1_b, ln_x, MV);
    hipLaunchKernelGGL(k_q, dim3(NQ / 8), dim3(256), 0, stream,
                       ln_x, coords, qidx, w_pos, b_pos, w_q, b_q,
                       pos_qx, pos_qy, pos_qz, qbuf, qp);
    hipLaunchKernelGGL(HIP_KERNEL_NAME(k_gemm<0>), dim3(4, NG / 128), dim3(256), 0, stream,
                       ln_x, gidx, mask_i, w_kv_t, b_k, (const float*)nullptr,
                       kmat, (unsigned short*)nullptr);
    hipLaunchKernelGGL(k_attn, dim3(NQ / 4), dim3(256), 0, stream,
                       qbuf, qp, kmat, mask_i, rel_x, rel_y, rel_z,
                       pos_kx, pos_ky, pos_kz, attn);
    hipLaunchKernelGGL(HIP_KERNEL_NAME(k_gemm<1>), dim3(4, NG / 128), dim3(256), 0, stream,
                       ln_x, gidx, mask_i, w_kv_t, b_v, attn,
                       (unsigned short*)nullptr, attnln);
    // proj: act = attn_bf16 @ wp_t + b_proj + vox[qidx]
    hipLaunchKernelGGL(HIP_KERNEL_NAME(k_mm<256, 2>), dim3(4, NQ / 128), dim3(256), 0, stream,
                       attnln, wp_t, b_proj, vox, qidx,
                       (unsigned short*)nullptr, actbuf);
    hipLaunchKernelGGL(k_ln, dim3(NQ / 4), dim3(256), 0, stream,
                       actbuf, ln2_g, ln2_b, actln, NQ);
    // FF1: h = relu(actln @ w1_t + b_ff1)
    hipLaunchKernelGGL(HIP_KERNEL_NAME(k_mm<256, 0>), dim3(8, NQ / 128), dim3(256), 0, stream,
                       actln, w1_t, b_ff1, (const float*)nullptr, (const int*)nullptr,
                       hbuf, (float*)nullptr);
    // FF2: out = h @ w2_t + b_ff2 + act
    hipLaunchKernelGGL(HIP_KERNEL_NAME(k_mm<512, 1>), dim3(4, NQ / 128), dim3(256), 0, stream,
                       hbuf, w2_t, b_ff2, actbuf, (const int*)nullptr,
                       (unsigned short*)nullptr, (float*)d_out);
}

// Round 5
// 523.375 us; speedup vs baseline: 1.1025x; 1.0779x over previous
//
#include <hip/hip_runtime.h>
#include <hip/hip_bf16.h>
#include <math.h>

// Problem constants (fixed by the reference)
#define MV   100000          // voxels
#define NQ   8192            // queries
#define KN   32              // neighbors per query
#define CH   256             // channels
#define NH   8               // heads
#define DHD  32              // head dim
#define FFD  512             // FF hidden
#define NG   (NQ*KN)         // 262144 gathered rows
#define QPW  37              // 15+15+7 rel-pos columns per head (q-side)
#define QPN  (NH*QPW)        // 296
#define ASTR 40              // padded LDS stride for k_mm (kept from R4)

typedef __bf16 bf16x8 __attribute__((ext_vector_type(8)));
typedef float  f32x4  __attribute__((ext_vector_type(4)));

__device__ __forceinline__ float bf2f(unsigned short u) {
    return __uint_as_float(((unsigned int)u) << 16);
}
__device__ __forceinline__ unsigned short f2bf(float f) {
    unsigned int x = __float_as_uint(f);
    unsigned int r = x + 0x7FFFu + ((x >> 16) & 1u);   // RNE
    return (unsigned short)(r >> 16);
}
// async global->LDS, 16 B per lane; LDS dest = wave-uniform base + lane*16
__device__ __forceinline__ void glds16(const unsigned short* g, unsigned short* l) {
    __builtin_amdgcn_global_load_lds(
        (const __attribute__((address_space(1))) void*)g,
        (__attribute__((address_space(3))) void*)l, 16, 0, 0);
}

// ---------------------------------------------------------------------------
// k_detect_mask: gather_mask may ship as int32 (0/1) or raw 1-byte bools.
// ---------------------------------------------------------------------------
__global__ __launch_bounds__(256) void k_detect_mask(const unsigned char* __restrict__ raw,
                                                     int* __restrict__ flags) {
    __shared__ int any;
    if (threadIdx.x == 0) any = 0;
    __syncthreads();
    const uint4* p = (const uint4*)raw;             // NG bytes = 16384 uint4
    int i = blockIdx.x * 256 + threadIdx.x;
    uint4 v = p[i];
    if ((v.x | v.y | v.z | v.w) & 0xFFFFFF00u) any = 1;
    __syncthreads();
    if (threadIdx.x == 0) flags[blockIdx.x] = any;
}

// ---------------------------------------------------------------------------
// k_prep: int mask (layout-adaptive) + bf16 col-major (B-layout) weights
// + zero-row init (masked-lane target for global_load_lds).
// ---------------------------------------------------------------------------
__global__ __launch_bounds__(256) void k_prep(const float* __restrict__ w_k,
                                              const float* __restrict__ w_v,
                                              const float* __restrict__ w_ff1,
                                              const float* __restrict__ w_ff2,
                                              const float* __restrict__ w_proj,
                                              const void* __restrict__ mask_raw,
                                              const int* __restrict__ flags,
                                              unsigned short* __restrict__ w_kv_t,
                                              unsigned short* __restrict__ w1_t,
                                              unsigned short* __restrict__ w2_t,
                                              unsigned short* __restrict__ wp_t,
                                              unsigned short* __restrict__ zrow,
                                              int* __restrict__ mask_i) {
    __shared__ int bl;
    if (threadIdx.x == 0) {
        int a = 0;
        #pragma unroll 8
        for (int i = 0; i < 64; i++) a |= flags[i];
        bl = a;
    }
    __syncthreads();
    int byteLayout = bl;
    int idx = blockIdx.x * 256 + threadIdx.x;       // grid 1024 -> 262144
    if (blockIdx.x == 0 && threadIdx.x < 32)
        ((uint4*)zrow)[threadIdx.x] = (uint4){0u, 0u, 0u, 0u};   // 512 B zeros
    if (idx < NG) {
        int mv = byteLayout ? (int)((const unsigned char*)mask_raw)[idx]
                            : ((const int*)mask_raw)[idx];
        mask_i[idx] = (mv != 0) ? 1 : 0;
    }
    if (idx < 512 * 256) {
        int col = idx >> 8, j = idx & 255;
        float v = (col < 256) ? w_k[j * 256 + col] : w_v[j * 256 + (col - 256)];
        w_kv_t[idx] = f2bf(v);
    }
    if (idx < 512 * 256) {
        int n = idx >> 8, k = idx & 255;
        w1_t[idx] = f2bf(w_ff1[k * FFD + n]);
    }
    if (idx < 256 * 512) {
        int n = idx >> 9, k = idx & 511;
        w2_t[idx] = f2bf(w_ff2[k * CH + n]);
    }
    if (idx < 256 * 256) {
        int n = idx >> 8, k = idx & 255;
        wp_t[idx] = f2bf(w_proj[k * CH + n]);
    }
}

// ---------------------------------------------------------------------------
// k_posc: comb[h][rx][ry][rz][d] = pos_kx[h][d][rx]+pos_ky[h][d][ry]+pos_kz[h][d][rz]
// 8*15*15*7*32 = 403200 floats (1.6 MB, L2-resident in k_attn).
// ---------------------------------------------------------------------------
__global__ __launch_bounds__(256) void k_posc(const float* __restrict__ pos_kx,
                                              const float* __restrict__ pos_ky,
                                              const float* __restrict__ pos_kz,
                                              float* __restrict__ comb) {
    int idx = blockIdx.x * 256 + threadIdx.x;
    if (idx >= 8 * 15 * 15 * 7 * 32) return;
    int d = idx & 31, r = idx >> 5;
    int rz = r % 7;  r /= 7;
    int ry = r % 15; r /= 15;
    int rx = r % 15; int h = r / 15;
    comb[idx] = pos_kx[(h * DHD + d) * 15 + rx]
              + pos_ky[(h * DHD + d) * 15 + ry]
              + pos_kz[(h * DHD + d) * 7  + rz];
}

// ---------------------------------------------------------------------------
// k_ln: LayerNorm rows of x[nrows][256] -> bf16. One wave per row.
// ---------------------------------------------------------------------------
__global__ __launch_bounds__(256) void k_ln(const float* __restrict__ x,
                                            const float* __restrict__ g,
                                            const float* __restrict__ b,
                                            unsigned short* __restrict__ o,
                                            int nrows) {
    int wid = threadIdx.x >> 6, lane = threadIdx.x & 63;
    int row = blockIdx.x * 4 + wid;
    if (row >= nrows) return;
    const float4 v = *(const float4*)(x + (size_t)row * CH + lane * 4);
    float s  = v.x + v.y + v.z + v.w;
    float sq = v.x * v.x + v.y * v.y + v.z * v.z + v.w * v.w;
    #pragma unroll
    for (int off = 1; off < 64; off <<= 1) {
        s  += __shfl_xor(s,  off);
        sq += __shfl_xor(sq, off);
    }
    float mu  = s * (1.f / CH);
    float var = sq * (1.f / CH) - mu * mu;
    float rs  = rsqrtf(var + 1e-5f);
    float4 gv = *(const float4*)(g + lane * 4);
    float4 bv = *(const float4*)(b + lane * 4);
    ushort4 ov;
    ov.x = f2bf((v.x - mu) * rs * gv.x + bv.x);
    ov.y = f2bf((v.y - mu) * rs * gv.y + bv.y);
    ov.z = f2bf((v.z - mu) * rs * gv.z + bv.z);
    ov.w = f2bf((v.w - mu) * rs * gv.w + bv.w);
    *(ushort4*)(o + (size_t)row * CH + lane * 4) = ov;
}

// ---------------------------------------------------------------------------
// k_q: q = (ln_x[qi]+relu(pos))@w_q + b_q (fp32) + q-side rel tables qp.
// ---------------------------------------------------------------------------
__global__ __launch_bounds__(256) void k_q(const unsigned short* __restrict__ ln_x,
                                           const float* __restrict__ coords,
                                           const int* __restrict__ qidx,
                                           const float* __restrict__ w_pos,
                                           const float* __restrict__ b_pos,
                                           const float* __restrict__ w_q,
                                           const float* __restrict__ b_q,
                                           const float* __restrict__ pos_qx,
                                           const float* __restrict__ pos_qy,
                                           const float* __restrict__ pos_qz,
                                           float* __restrict__ qout,
                                           float* __restrict__ qp) {
    __shared__ float qin_s[8 * CH];
    __shared__ float q_s[8 * CH];
    int c = threadIdx.x;
    int nb = blockIdx.x * 8;
    float wp0 = w_pos[c], wp1 = w_pos[CH + c], wp2 = w_pos[2 * CH + c], bp = b_pos[c];
    #pragma unroll
    for (int qq = 0; qq < 8; qq++) {
        int n = nb + qq;
        float p = bp + coords[n * 3] * wp0 + coords[n * 3 + 1] * wp1 + coords[n * 3 + 2] * wp2;
        p = fmaxf(p, 0.f);
        int qi = qidx[n];
        qin_s[qq * CH + c] = bf2f(ln_x[(size_t)qi * CH + c]) + p;
    }
    __syncthreads();
    float acc[8];
    float bq = b_q[c];
    #pragma unroll
    for (int qq = 0; qq < 8; qq++) acc[qq] = bq;
    #pragma unroll 4
    for (int j = 0; j < CH; j++) {
        float w = w_q[j * CH + c];
        #pragma unroll
        for (int qq = 0; qq < 8; qq++) acc[qq] += qin_s[qq * CH + j] * w;
    }
    #pragma unroll
    for (int qq = 0; qq < 8; qq++) {
        qout[(size_t)(nb + qq) * CH + c] = acc[qq];
        q_s[qq * CH + c] = acc[qq];
    }
    __syncthreads();
    for (int t = threadIdx.x; t < 8 * QPN; t += 256) {
        int qq = t / QPN, u = t % QPN;
        int h = u / QPW, r = u % QPW;
        const float* tab; int rr, R;
        if (r < 15)      { tab = pos_qx; rr = r;      R = 15; }
        else if (r < 30) { tab = pos_qy; rr = r - 15; R = 15; }
        else             { tab = pos_qz; rr = r - 30; R = 7;  }
        float a = 0.f;
        const float* qrow = q_s + qq * CH + h * DHD;
        #pragma unroll
        for (int d = 0; d < DHD; d++) a += qrow[d] * tab[(h * DHD + d) * R + rr];
        qp[(size_t)(nb + qq) * QPN + u] = a;
    }
}

// ---------------------------------------------------------------------------
// k_gemm<MODE>: gathered-row GEMM, m97-style structure.
// Tile 128 rows x 128 cols, BK=32, 4 waves in 2x2 (wave wr,wc computes a
// 64x64 sub-tile = 4x4 MFMA frags). Staging via global_load_lds width-16:
// per wave 2 A-issues + 2 B-issues of 1024 B. Masked rows point their lane
// addresses at zrow (512 B of zeros, L1-hit) -> branch-free, no HBM fetch.
//   MODE 0: k = A@w_k + b_k -> bf16 kmat[NG][256]  (masked-row stores skipped)
//   MODE 1: attnout_bf[n][c] = bf16( sum_k attn[n,h(c),k]*v[k][c] + b_v[c] )
// ---------------------------------------------------------------------------
template <int MODE>
__global__ __launch_bounds__(256) void k_gemm(const unsigned short* __restrict__ ln_x,
                                              const int* __restrict__ gidx,
                                              const int* __restrict__ mask_i,
                                              const unsigned short* __restrict__ w_kv_t,
                                              const unsigned short* __restrict__ zrow,
                                              const float* __restrict__ bias,
                                              const float* __restrict__ attn,
                                              unsigned short* __restrict__ kout,
                                              unsigned short* __restrict__ attnout_bf) {
    __shared__ __align__(16) unsigned short As[128 * 32];   // row-major, stride 32 (glds layout)
    __shared__ __align__(16) unsigned short Bs[128 * 32];   // col-major, stride 32
    __shared__ float attn_s[4 * 256];                       // MODE 1 only
    __shared__ int   msk_s[128];
    const int tid = threadIdx.x;
    const int w = tid >> 6, l = tid & 63;
    const int wr = w >> 1, wc = w & 1;
    const int rowbase = blockIdx.y * 128;
    const int col0   = blockIdx.x * 128;
    const int col0_w = col0 + (MODE ? 256 : 0);

    // staging lane assignment: lane covers row/col (w*16 + (l>>2)), quarter l&3
    const int sr = l >> 2, sq = l & 3;
    const int ra0 = w * 16 + sr, ra1 = 64 + w * 16 + sr;
    int m0 = mask_i[rowbase + ra0];
    int m1 = mask_i[rowbase + ra1];
    const unsigned short* pa0 =
        (m0 ? zrow : ln_x + (size_t)gidx[rowbase + ra0] * CH) + sq * 8;
    const unsigned short* pa1 =
        (m1 ? zrow : ln_x + (size_t)gidx[rowbase + ra1] * CH) + sq * 8;
    const unsigned short* pb0 = w_kv_t + (size_t)(col0_w + w * 16 + sr) * CH + sq * 8;
    const unsigned short* pb1 = w_kv_t + (size_t)(col0_w + 64 + w * 16 + sr) * CH + sq * 8;
    unsigned short* lA0 = As + w * 512;           // bytes: w*1024
    unsigned short* lA1 = As + 2048 + w * 512;    // bytes: 4096 + w*1024
    unsigned short* lB0 = Bs + w * 512;
    unsigned short* lB1 = Bs + 2048 + w * 512;

    if (tid < 128) msk_s[tid] = mask_i[rowbase + tid];
    if (MODE) {
        for (int i = tid; i < 1024; i += 256)
            attn_s[i] = attn[(size_t)blockIdx.y * 1024 + i];
    }

    f32x4 acc[4][4];
    #pragma unroll
    for (int mt = 0; mt < 4; mt++)
        #pragma unroll
        for (int nt = 0; nt < 4; nt++)
            acc[mt][nt] = (f32x4){0.f, 0.f, 0.f, 0.f};

    const int ml = l & 15, qd = l >> 4;
    for (int kk = 0; kk < CH; kk += 32) {
        __syncthreads();
        glds16(pa0 + kk, lA0);
        glds16(pa1 + kk, lA1);
        glds16(pb0 + kk, lB0);
        glds16(pb1 + kk, lB1);
        __syncthreads();                          // drains vmcnt -> LDS visible
        bf16x8 af[4], bf[4];
        #pragma unroll
        for (int mt = 0; mt < 4; mt++)
            af[mt] = *(const bf16x8*)(As + (wr * 64 + mt * 16 + ml) * 32 + qd * 8);
        #pragma unroll
        for (int nt = 0; nt < 4; nt++)
            bf[nt] = *(const bf16x8*)(Bs + (wc * 64 + nt * 16 + ml) * 32 + qd * 8);
        #pragma unroll
        for (int mt = 0; mt < 4; mt++)
            #pragma unroll
            for (int nt = 0; nt < 4; nt++)
                acc[mt][nt] = __builtin_amdgcn_mfma_f32_16x16x32_bf16(af[mt], bf[nt], acc[mt][nt], 0, 0, 0);
    }

    if (MODE == 0) {
        #pragma unroll
        for (int nt = 0; nt < 4; nt++) {
            int col = col0 + wc * 64 + nt * 16 + ml;
            float bk = bias[col];
            #pragma unroll
            for (int mt = 0; mt < 4; mt++) {
                int rl = wr * 64 + mt * 16 + qd * 4;
                #pragma unroll
                for (int i = 0; i < 4; i++)
                    if (!msk_s[rl + i])                  // skip masked-row stores
                        kout[(size_t)(rowbase + rl + i) * CH + col] = f2bf(acc[mt][nt][i] + bk);
            }
        }
    } else {
        // wave wr covers queries by*4 + wr*2 + {0,1}; mt 0,1 -> qs 0; mt 2,3 -> qs 1
        #pragma unroll
        for (int nt = 0; nt < 4; nt++) {
            int col = col0 + wc * 64 + nt * 16 + ml;
            int h = col >> 5;
            #pragma unroll
            for (int qs = 0; qs < 2; qs++) {
                int q = wr * 2 + qs;
                float ps = 0.f;
                #pragma unroll
                for (int mh = 0; mh < 2; mh++) {
                    int mt = qs * 2 + mh;
                    #pragma unroll
                    for (int i = 0; i < 4; i++) {
                        int kkk = mh * 16 + qd * 4 + i;
                        ps += attn_s[q * 256 + (h << 5) + kkk] * acc[mt][nt][i];
                    }
                }
                ps += __shfl_xor(ps, 16);
                ps += __shfl_xor(ps, 32);
                if (qd == 0)
                    attnout_bf[(size_t)(blockIdx.y * 4 + q) * CH + col] = f2bf(ps + bias[col]);
            }
        }
    }
}

// ---------------------------------------------------------------------------
// k_mm<KD,EPI>: plain row GEMM, A[8192][KD] bf16 @ Bt[cols][KD] bf16.
//   EPI 0: relu -> bf16 at ld FFD (FF1)   EPI 1: +bias+res -> fp32 (FF2)
//   EPI 2: +bias+res[qidx[row]] -> fp32 (proj)
// ---------------------------------------------------------------------------
template <int KD, int EPI>
__global__ __launch_bounds__(256) void k_mm(const unsigned short* __restrict__ A,
                                            const unsigned short* __restrict__ Bt_g,
                                            const float* __restrict__ bias,
                                            const float* __restrict__ res,
                                            const int* __restrict__ qidx,
                                            unsigned short* __restrict__ out_bf,
                                            float* __restrict__ out_f) {
    __shared__ __align__(16) unsigned short As[128 * ASTR];
    __shared__ __align__(16) unsigned short Bs[64 * ASTR];
    int tid = threadIdx.x;
    int w = tid >> 6, l = tid & 63;
    int rowbase = blockIdx.y * 128;
    int col0 = blockIdx.x * 64;
    int r0 = tid >> 2, qt = tid & 3;
    const unsigned short* a0p = A + (size_t)(rowbase + r0) * KD + qt * 8;
    const unsigned short* a1p = A + (size_t)(rowbase + 64 + r0) * KD + qt * 8;

    f32x4 acc[2][4];
    #pragma unroll
    for (int mt = 0; mt < 2; mt++)
        #pragma unroll
        for (int nt = 0; nt < 4; nt++)
            acc[mt][nt] = (f32x4){0.f, 0.f, 0.f, 0.f};

    const int ml = l & 15, qd = l >> 4;
    for (int kk = 0; kk < KD; kk += 32) {
        __syncthreads();
        uint4 v0 = *(const uint4*)(a0p + kk);
        uint4 v1 = *(const uint4*)(a1p + kk);
        *(uint4*)(As + r0 * ASTR + qt * 8)        = v0;
        *(uint4*)(As + (64 + r0) * ASTR + qt * 8) = v1;
        {
            uint4 bv = *(const uint4*)(Bt_g + (size_t)(col0 + r0) * KD + kk + qt * 8);
            *(uint4*)(Bs + r0 * ASTR + qt * 8) = bv;
        }
        __syncthreads();
        bf16x8 a0 = *(const bf16x8*)(As + (w * 32 + ml) * ASTR + qd * 8);
        bf16x8 a1 = *(const bf16x8*)(As + (w * 32 + 16 + ml) * ASTR + qd * 8);
        #pragma unroll
        for (int nt = 0; nt < 4; nt++) {
            bf16x8 bb = *(const bf16x8*)(Bs + (nt * 16 + ml) * ASTR + qd * 8);
            acc[0][nt] = __builtin_amdgcn_mfma_f32_16x16x32_bf16(a0, bb, acc[0][nt], 0, 0, 0);
            acc[1][nt] = __builtin_amdgcn_mfma_f32_16x16x32_bf16(a1, bb, acc[1][nt], 0, 0, 0);
        }
    }

    #pragma unroll
    for (int nt = 0; nt < 4; nt++) {
        int col = col0 + nt * 16 + ml;
        float bv = bias[col];
        #pragma unroll
        for (int mt = 0; mt < 2; mt++) {
            int rl = w * 32 + mt * 16 + qd * 4;
            #pragma unroll
            for (int i = 0; i < 4; i++) {
                int row = rowbase + rl + i;
                float v = acc[mt][nt][i] + bv;
                if (EPI == 0) {
                    out_bf[(size_t)row * FFD + col] = f2bf(fmaxf(v, 0.f));
                } else if (EPI == 1) {
                    out_f[(size_t)row * CH + col] = v + res[(size_t)row * CH + col];
                } else {
                    int qi = qidx[row];
                    out_f[(size_t)row * CH + col] = v + res[(size_t)qi * CH + col];
                }
            }
        }
    }
}

// ---------------------------------------------------------------------------
// k_attn: logits = q.k*DH^-0.5 + qp gathers + dot(k, comb-row); mask -> e=0;
// softmax over K. comb replaces the 3 per-axis LDS table gathers.
// ---------------------------------------------------------------------------
__global__ __launch_bounds__(256) void k_attn(const float* __restrict__ qbuf,
                                              const float* __restrict__ qp,
                                              const unsigned short* __restrict__ kmat,
                                              const int* __restrict__ mask_i,
                                              const int* __restrict__ rel_x,
                                              const int* __restrict__ rel_y,
                                              const int* __restrict__ rel_z,
                                              const float* __restrict__ comb,
                                              float* __restrict__ attn) {
    __shared__ float q_s[1024];
    __shared__ float qp_s[4 * QPN];
    int tid = threadIdx.x;
    int qb = blockIdx.x * 4;
    for (int i = tid; i < 1024; i += 256) q_s[i] = qbuf[(size_t)qb * CH + i];
    for (int i = tid; i < 4 * QPN; i += 256) qp_s[i] = qp[(size_t)qb * QPN + i];
    __syncthreads();
    int h = tid >> 5, k = tid & 31;
    const float scale = 0.17677669529663687f;   // 32^-0.5
    for (int qq = 0; qq < 4; qq++) {
        int n = qb + qq;
        int gi = n * KN + k;
        int mk = mask_i[gi];
        float lg = -1e9f;
        if (!mk) {
            int rx = rel_x[gi], ry = rel_y[gi], rz = rel_z[gi];
            const uint4* kp = (const uint4*)(kmat + (size_t)gi * CH + h * DHD);
            float kv[32];
            #pragma unroll
            for (int j = 0; j < 4; j++) {
                uint4 u = kp[j];
                kv[j * 8 + 0] = bf2f((unsigned short)(u.x & 0xFFFF));
                kv[j * 8 + 1] = bf2f((unsigned short)(u.x >> 16));
                kv[j * 8 + 2] = bf2f((unsigned short)(u.y & 0xFFFF));
                kv[j * 8 + 3] = bf2f((unsigned short)(u.y >> 16));
                kv[j * 8 + 4] = bf2f((unsigned short)(u.z & 0xFFFF));
                kv[j * 8 + 5] = bf2f((unsigned short)(u.z >> 16));
                kv[j * 8 + 6] = bf2f((unsigned short)(u.w & 0xFFFF));
                kv[j * 8 + 7] = bf2f((unsigned short)(u.w >> 16));
            }
            const float* cp = comb + ((((h * 15 + rx) * 15 + ry) * 7 + rz) << 5);
            float s1 = 0.f, s2 = 0.f;
            const float* qrow = q_s + qq * CH + h * DHD;
            #pragma unroll
            for (int d = 0; d < 32; d++) {
                s1 += kv[d] * qrow[d];
                s2 += kv[d] * cp[d];
            }
            lg = s1 * scale + s2
               + qp_s[qq * QPN + h * QPW + rx]
               + qp_s[qq * QPN + h * QPW + 15 + ry]
               + qp_s[qq * QPN + h * QPW + 30 + rz];
        }
        float mx = lg;
        #pragma unroll
        for (int off = 1; off <= 16; off <<= 1) mx = fmaxf(mx, __shfl_xor(mx, off));
        float e = mk ? 0.f : __expf(lg - mx);
        float sm = e;
        #pragma unroll
        for (int off = 1; off <= 16; off <<= 1) sm += __shfl_xor(sm, off);
        attn[(size_t)n * 256 + tid] = (sm > 0.f) ? e / sm : 0.f;
    }
}

// ---------------------------------------------------------------------------
extern "C" void kernel_launch(void* const* d_in, const int* in_sizes, int n_in,
                              void* d_out, int out_size, void* d_ws, size_t ws_size,
                              hipStream_t stream) {
    (void)in_sizes; (void)n_in; (void)out_size; (void)ws_size;
    const float* vox    = (const float*)d_in[0];
    const float* coords = (const float*)d_in[1];
    const int*   qidx   = (const int*)d_in[2];
    const int*   gidx   = (const int*)d_in[3];
    const void*  mraw   = d_in[4];
    const int*   rel_x  = (const int*)d_in[5];
    const int*   rel_y  = (const int*)d_in[6];
    const int*   rel_z  = (const int*)d_in[7];
    const float* w_pos  = (const float*)d_in[8];
    const float* b_pos  = (const float*)d_in[9];
    const float* w_q    = (const float*)d_in[10];
    const float* b_q    = (const float*)d_in[11];
    const float* w_k    = (const float*)d_in[12];
    const float* b_k    = (const float*)d_in[13];
    const float* w_v    = (const float*)d_in[14];
    const float* b_v    = (const float*)d_in[15];
    const float* w_proj = (const float*)d_in[16];
    const float* b_proj = (const float*)d_in[17];
    const float* ln1_g  = (const float*)d_in[18];
    const float* ln1_b  = (const float*)d_in[19];
    const float* ln2_g  = (const float*)d_in[20];
    const float* ln2_b  = (const float*)d_in[21];
    const float* w_ff1  = (const float*)d_in[22];
    const float* b_ff1  = (const float*)d_in[23];
    const float* w_ff2  = (const float*)d_in[24];
    const float* b_ff2  = (const float*)d_in[25];
    const float* pos_qx = (const float*)d_in[26];
    const float* pos_qy = (const float*)d_in[27];
    const float* pos_qz = (const float*)d_in[28];
    const float* pos_kx = (const float*)d_in[29];
    const float* pos_ky = (const float*)d_in[30];
    const float* pos_kz = (const float*)d_in[31];

    // workspace carve (~242 MB total)
    char* p = (char*)d_ws;
    auto take = [&](size_t n) { char* r = p; p += (n + 255) & ~(size_t)255; return r; };
    unsigned short* ln_x    = (unsigned short*)take((size_t)MV * CH * 2);   // 51.2 MB
    unsigned short* w_kv_t  = (unsigned short*)take((size_t)512 * 256 * 2);
    unsigned short* w1_t    = (unsigned short*)take((size_t)512 * 256 * 2);
    unsigned short* w2_t    = (unsigned short*)take((size_t)256 * 512 * 2);
    unsigned short* wp_t    = (unsigned short*)take((size_t)256 * 256 * 2);
    unsigned short* zrow    = (unsigned short*)take(512);
    int*            flags   = (int*)take(64 * 4);
    int*            mask_i  = (int*)take((size_t)NG * 4);                   // 1.05 MB
    float*          comb    = (float*)take((size_t)8 * 15 * 15 * 7 * 32 * 4); // 1.6 MB
    float*          qbuf    = (float*)take((size_t)NQ * CH * 4);            // 8.4 MB
    float*          qp      = (float*)take((size_t)NQ * QPN * 4);           // 9.7 MB
    unsigned short* kmat    = (unsigned short*)take((size_t)NG * CH * 2);   // 134 MB
    float*          attn    = (float*)take((size_t)NQ * 256 * 4);           // 8.4 MB
    unsigned short* attnln  = (unsigned short*)take((size_t)NQ * CH * 2);   // 4.2 MB
    float*          actbuf  = (float*)take((size_t)NQ * CH * 4);            // 8.4 MB
    unsigned short* actln   = (unsigned short*)take((size_t)NQ * CH * 2);   // 4.2 MB
    unsigned short* hbuf    = (unsigned short*)take((size_t)NQ * FFD * 2);  // 8.4 MB

    hipLaunchKernelGGL(k_detect_mask, dim3(64), dim3(256), 0, stream,
                       (const unsigned char*)mraw, flags);
    hipLaunchKernelGGL(k_prep, dim3(NG / 256), dim3(256), 0, stream,
                       w_k, w_v, w_ff1, w_ff2, w_proj, mraw, flags,
                       w_kv_t, w1_t, w2_t, wp_t, zrow, mask_i);
    hipLaunchKernelGGL(k_posc, dim3((8 * 15 * 15 * 7 * 32 + 255) / 256), dim3(256), 0, stream,
                       pos_kx, pos_ky, pos_kz, comb);
    hipLaunchKernelGGL(k_ln, dim3(MV / 4 + 1), dim3(256), 0, stream,
                       vox, ln1_g, ln1_b, ln_x, MV);
    hipLaunchKernelGGL(k_q, dim3(NQ / 8), dim3(256), 0, stream,
                       ln_x, coords, qidx, w_pos, b_pos, w_q, b_q,
                       pos_qx, pos_qy, pos_qz, qbuf, qp);
    hipLaunchKernelGGL(HIP_KERNEL_NAME(k_gemm<0>), dim3(2, NG / 128), dim3(256), 0, stream,
                       ln_x, gidx, mask_i, w_kv_t, zrow, b_k, (const float*)nullptr,
                       kmat, (unsigned short*)nullptr);
    hipLaunchKernelGGL(k_attn, dim3(NQ / 4), dim3(256), 0, stream,
                       qbuf, qp, kmat, mask_i, rel_x, rel_y, rel_z, comb, attn);
    hipLaunchKernelGGL(HIP_KERNEL_NAME(k_gemm<1>), dim3(2, NG / 128), dim3(256), 0, stream,
                       ln_x, gidx, mask_i, w_kv_t, zrow, b_v, attn,
                       (unsigned short*)nullptr, attnln);
    // proj: act = attn_bf16 @ wp_t + b_proj + vox[qidx]
    hipLaunchKernelGGL(HIP_KERNEL_NAME(k_mm<256, 2>), dim3(4, NQ / 128), dim3(256), 0, stream,
                       attnln, wp_t, b_proj, vox, qidx,
                       (unsigned short*)nullptr, actbuf);
    hipLaunchKernelGGL(k_ln, dim3(NQ / 4), dim3(256), 0, stream,
                       actbuf, ln2_g, ln2_b, actln, NQ);
    // FF1: h = relu(actln @ w1_t + b_ff1)
    hipLaunchKernelGGL(HIP_KERNEL_NAME(k_mm<256, 0>), dim3(8, NQ / 128), dim3(256), 0, stream,
                       actln, w1_t, b_ff1, (const float*)nullptr, (const int*)nullptr,
                       hbuf, (float*)nullptr);
    // FF2: out = h @ w2_t + b_ff2 + act
    hipLaunchKernelGGL(HIP_KERNEL_NAME(k_mm<512, 1>), dim3(4, NQ / 128), dim3(256), 0, stream,
                       hbuf, w2_t, b_ff2, actbuf, (const int*)nullptr,
                       (unsigned short*)nullptr, (float*)d_out);
}

// Round 6
// 456.838 us; speedup vs baseline: 1.2631x; 1.1456x over previous
//
#include <hip/hip_runtime.h>
#include <hip/hip_bf16.h>
#include <math.h>

// Problem constants (fixed by the reference)
#define MV   100000          // voxels
#define NQ   8192            // queries
#define KN   32              // neighbors per query
#define CH   256             // channels
#define NH   8               // heads
#define DHD  32              // head dim
#define FFD  512             // FF hidden
#define NG   (NQ*KN)         // 262144 gathered rows
#define QPW  37              // 15+15+7 rel-pos columns per head (q-side)
#define QPN  (NH*QPW)        // 296
#define ASTR 40              // padded LDS stride for k_mm

typedef __bf16 bf16x8 __attribute__((ext_vector_type(8)));
typedef float  f32x4  __attribute__((ext_vector_type(4)));

__device__ __forceinline__ float bf2f(unsigned short u) {
    return __uint_as_float(((unsigned int)u) << 16);
}
__device__ __forceinline__ unsigned short f2bf(float f) {
    unsigned int x = __float_as_uint(f);
    unsigned int r = x + 0x7FFFu + ((x >> 16) & 1u);   // RNE
    return (unsigned short)(r >> 16);
}
// async global->LDS, 16 B per lane; LDS dest = wave-uniform base + lane*16
__device__ __forceinline__ void glds16(const unsigned short* g, unsigned short* l) {
    __builtin_amdgcn_global_load_lds(
        (const __attribute__((address_space(1))) void*)g,
        (__attribute__((address_space(3))) void*)l, 16, 0, 0);
}

// ---------------------------------------------------------------------------
// k_detect_mask: gather_mask may ship as int32 (0/1) or raw 1-byte bools.
// ---------------------------------------------------------------------------
__global__ __launch_bounds__(256) void k_detect_mask(const unsigned char* __restrict__ raw,
                                                     int* __restrict__ flags) {
    __shared__ int any;
    if (threadIdx.x == 0) any = 0;
    __syncthreads();
    const uint4* p = (const uint4*)raw;             // NG bytes = 16384 uint4
    int i = blockIdx.x * 256 + threadIdx.x;
    uint4 v = p[i];
    if ((v.x | v.y | v.z | v.w) & 0xFFFFFF00u) any = 1;
    __syncthreads();
    if (threadIdx.x == 0) flags[blockIdx.x] = any;
}

// ---------------------------------------------------------------------------
// k_prep: int mask (layout-adaptive) + bf16 col-major (B-layout) weights
// + bkv = [b_k | b_v] (512 floats).
// ---------------------------------------------------------------------------
__global__ __launch_bounds__(256) void k_prep(const float* __restrict__ w_k,
                                              const float* __restrict__ w_v,
                                              const float* __restrict__ w_ff1,
                                              const float* __restrict__ w_ff2,
                                              const float* __restrict__ w_proj,
                                              const float* __restrict__ b_k,
                                              const float* __restrict__ b_v,
                                              const void* __restrict__ mask_raw,
                                              const int* __restrict__ flags,
                                              unsigned short* __restrict__ w_kv_t,
                                              unsigned short* __restrict__ w1_t,
                                              unsigned short* __restrict__ w2_t,
                                              unsigned short* __restrict__ wp_t,
                                              float* __restrict__ bkv,
                                              int* __restrict__ mask_i) {
    __shared__ int bl;
    if (threadIdx.x == 0) {
        int a = 0;
        #pragma unroll 8
        for (int i = 0; i < 64; i++) a |= flags[i];
        bl = a;
    }
    __syncthreads();
    int byteLayout = bl;
    int idx = blockIdx.x * 256 + threadIdx.x;       // grid 1024 -> 262144
    if (blockIdx.x == 0 && threadIdx.x < 512)
        bkv[threadIdx.x] = (threadIdx.x < 256) ? b_k[threadIdx.x]
                                               : b_v[threadIdx.x - 256];
    if (idx < NG) {
        int mv = byteLayout ? (int)((const unsigned char*)mask_raw)[idx]
                            : ((const int*)mask_raw)[idx];
        mask_i[idx] = (mv != 0) ? 1 : 0;
    }
    if (idx < 512 * 256) {
        int col = idx >> 8, j = idx & 255;
        float v = (col < 256) ? w_k[j * 256 + col] : w_v[j * 256 + (col - 256)];
        w_kv_t[idx] = f2bf(v);
    }
    if (idx < 512 * 256) {
        int n = idx >> 8, k = idx & 255;
        w1_t[idx] = f2bf(w_ff1[k * FFD + n]);
    }
    if (idx < 256 * 512) {
        int n = idx >> 9, k = idx & 511;
        w2_t[idx] = f2bf(w_ff2[k * CH + n]);
    }
    if (idx < 256 * 256) {
        int n = idx >> 8, k = idx & 255;
        wp_t[idx] = f2bf(w_proj[k * CH + n]);
    }
}

// ---------------------------------------------------------------------------
// k_posc: comb[h][rx][ry][rz][d] = pos_kx[h][d][rx]+pos_ky[h][d][ry]+pos_kz[h][d][rz]
// ---------------------------------------------------------------------------
__global__ __launch_bounds__(256) void k_posc(const float* __restrict__ pos_kx,
                                              const float* __restrict__ pos_ky,
                                              const float* __restrict__ pos_kz,
                                              float* __restrict__ comb) {
    int idx = blockIdx.x * 256 + threadIdx.x;
    if (idx >= 8 * 15 * 15 * 7 * 32) return;
    int d = idx & 31, r = idx >> 5;
    int rz = r % 7;  r /= 7;
    int ry = r % 15; r /= 15;
    int rx = r % 15; int h = r / 15;
    comb[idx] = pos_kx[(h * DHD + d) * 15 + rx]
              + pos_ky[(h * DHD + d) * 15 + ry]
              + pos_kz[(h * DHD + d) * 7  + rz];
}

// ---------------------------------------------------------------------------
// k_ln: LayerNorm rows of x[nrows][256] -> bf16. One wave per row.
// ---------------------------------------------------------------------------
__global__ __launch_bounds__(256) void k_ln(const float* __restrict__ x,
                                            const float* __restrict__ g,
                                            const float* __restrict__ b,
                                            unsigned short* __restrict__ o,
                                            int nrows) {
    int wid = threadIdx.x >> 6, lane = threadIdx.x & 63;
    int row = blockIdx.x * 4 + wid;
    if (row >= nrows) return;
    const float4 v = *(const float4*)(x + (size_t)row * CH + lane * 4);
    float s  = v.x + v.y + v.z + v.w;
    float sq = v.x * v.x + v.y * v.y + v.z * v.z + v.w * v.w;
    #pragma unroll
    for (int off = 1; off < 64; off <<= 1) {
        s  += __shfl_xor(s,  off);
        sq += __shfl_xor(sq, off);
    }
    float mu  = s * (1.f / CH);
    float var = sq * (1.f / CH) - mu * mu;
    float rs  = rsqrtf(var + 1e-5f);
    float4 gv = *(const float4*)(g + lane * 4);
    float4 bv = *(const float4*)(b + lane * 4);
    ushort4 ov;
    ov.x = f2bf((v.x - mu) * rs * gv.x + bv.x);
    ov.y = f2bf((v.y - mu) * rs * gv.y + bv.y);
    ov.z = f2bf((v.z - mu) * rs * gv.z + bv.z);
    ov.w = f2bf((v.w - mu) * rs * gv.w + bv.w);
    *(ushort4*)(o + (size_t)row * CH + lane * 4) = ov;
}

// ---------------------------------------------------------------------------
// k_q: q = (ln_x[qi]+relu(pos))@w_q + b_q (fp32) + q-side rel tables qp.
// ---------------------------------------------------------------------------
__global__ __launch_bounds__(256) void k_q(const unsigned short* __restrict__ ln_x,
                                           const float* __restrict__ coords,
                                           const int* __restrict__ qidx,
                                           const float* __restrict__ w_pos,
                                           const float* __restrict__ b_pos,
                                           const float* __restrict__ w_q,
                                           const float* __restrict__ b_q,
                                           const float* __restrict__ pos_qx,
                                           const float* __restrict__ pos_qy,
                                           const float* __restrict__ pos_qz,
                                           float* __restrict__ qout,
                                           float* __restrict__ qp) {
    __shared__ float qin_s[8 * CH];
    __shared__ float q_s[8 * CH];
    int c = threadIdx.x;
    int nb = blockIdx.x * 8;
    float wp0 = w_pos[c], wp1 = w_pos[CH + c], wp2 = w_pos[2 * CH + c], bp = b_pos[c];
    #pragma unroll
    for (int qq = 0; qq < 8; qq++) {
        int n = nb + qq;
        float p = bp + coords[n * 3] * wp0 + coords[n * 3 + 1] * wp1 + coords[n * 3 + 2] * wp2;
        p = fmaxf(p, 0.f);
        int qi = qidx[n];
        qin_s[qq * CH + c] = bf2f(ln_x[(size_t)qi * CH + c]) + p;
    }
    __syncthreads();
    float acc[8];
    float bq = b_q[c];
    #pragma unroll
    for (int qq = 0; qq < 8; qq++) acc[qq] = bq;
    #pragma unroll 4
    for (int j = 0; j < CH; j++) {
        float w = w_q[j * CH + c];
        #pragma unroll
        for (int qq = 0; qq < 8; qq++) acc[qq] += qin_s[qq * CH + j] * w;
    }
    #pragma unroll
    for (int qq = 0; qq < 8; qq++) {
        qout[(size_t)(nb + qq) * CH + c] = acc[qq];
        q_s[qq * CH + c] = acc[qq];
    }
    __syncthreads();
    for (int t = threadIdx.x; t < 8 * QPN; t += 256) {
        int qq = t / QPN, u = t % QPN;
        int h = u / QPW, r = u % QPW;
        const float* tab; int rr, R;
        if (r < 15)      { tab = pos_qx; rr = r;      R = 15; }
        else if (r < 30) { tab = pos_qy; rr = r - 15; R = 15; }
        else             { tab = pos_qz; rr = r - 30; R = 7;  }
        float a = 0.f;
        const float* qrow = q_s + qq * CH + h * DHD;
        #pragma unroll
        for (int d = 0; d < DHD; d++) a += qrow[d] * tab[(h * DHD + d) * R + rr];
        qp[(size_t)(nb + qq) * QPN + u] = a;
    }
}

// ---------------------------------------------------------------------------
// k_kv: DENSE projection of all voxels: kv[m][0:256]=ln_x@w_k+b_k,
// kv[m][256:512]=ln_x@w_v+b_v, bf16. Replaces both gathered GEMMs (each
// voxel was projected ~2.6x redundantly through a random-64B gather).
// Tile 128 rows x 128 cols (glds16 staging), grid (4, ceil(MV/128)).
// Epilogue: LDS transpose so stores are 256B contiguous (no RMW).
// ---------------------------------------------------------------------------
__global__ __launch_bounds__(256) void k_kv(const unsigned short* __restrict__ ln_x,
                                            const unsigned short* __restrict__ w_kv_t,
                                            const float* __restrict__ bkv,
                                            unsigned short* __restrict__ kv) {
    __shared__ __align__(16) unsigned short As[128 * 32];   // 8 KB
    __shared__ __align__(16) unsigned short Bs[128 * 32];   // 8 KB
    const int tid = threadIdx.x;
    const int w = tid >> 6, l = tid & 63;
    const int wr = w >> 1, wc = w & 1;
    const int rowbase = blockIdx.y * 128;
    const int col0 = blockIdx.x * 128;
    const int sr = l >> 2, sq = l & 3;
    int ra0 = rowbase + w * 16 + sr;      if (ra0 >= MV) ra0 = MV - 1;
    int ra1 = rowbase + 64 + w * 16 + sr; if (ra1 >= MV) ra1 = MV - 1;
    const unsigned short* pa0 = ln_x + (size_t)ra0 * CH + sq * 8;
    const unsigned short* pa1 = ln_x + (size_t)ra1 * CH + sq * 8;
    const unsigned short* pb0 = w_kv_t + (size_t)(col0 + w * 16 + sr) * CH + sq * 8;
    const unsigned short* pb1 = w_kv_t + (size_t)(col0 + 64 + w * 16 + sr) * CH + sq * 8;
    unsigned short* lA0 = As + w * 512;
    unsigned short* lA1 = As + 2048 + w * 512;
    unsigned short* lB0 = Bs + w * 512;
    unsigned short* lB1 = Bs + 2048 + w * 512;

    f32x4 acc[4][4];
    #pragma unroll
    for (int mt = 0; mt < 4; mt++)
        #pragma unroll
        for (int nt = 0; nt < 4; nt++)
            acc[mt][nt] = (f32x4){0.f, 0.f, 0.f, 0.f};

    const int ml = l & 15, qd = l >> 4;
    for (int kk = 0; kk < CH; kk += 32) {
        __syncthreads();
        glds16(pa0 + kk, lA0);
        glds16(pa1 + kk, lA1);
        glds16(pb0 + kk, lB0);
        glds16(pb1 + kk, lB1);
        __syncthreads();
        bf16x8 af[4], bf[4];
        #pragma unroll
        for (int mt = 0; mt < 4; mt++)
            af[mt] = *(const bf16x8*)(As + (wr * 64 + mt * 16 + ml) * 32 + qd * 8);
        #pragma unroll
        for (int nt = 0; nt < 4; nt++)
            bf[nt] = *(const bf16x8*)(Bs + (wc * 64 + nt * 16 + ml) * 32 + qd * 8);
        #pragma unroll
        for (int mt = 0; mt < 4; mt++)
            #pragma unroll
            for (int nt = 0; nt < 4; nt++)
                acc[mt][nt] = __builtin_amdgcn_mfma_f32_16x16x32_bf16(af[mt], bf[nt], acc[mt][nt], 0, 0, 0);
    }

    // epilogue: per-col bias, then LDS transpose -> coalesced 16B stores
    float bb[4];
    #pragma unroll
    for (int nt = 0; nt < 4; nt++)
        bb[nt] = bkv[col0 + wc * 64 + nt * 16 + ml];
    unsigned short* trs = As;                 // reuse 8 KB (2 bands x 16 x 128)
    #pragma unroll
    for (int mt = 0; mt < 4; mt++) {
        __syncthreads();                      // protect As reuse / prev pass
        #pragma unroll
        for (int nt = 0; nt < 4; nt++) {
            int lcol = wc * 64 + nt * 16 + ml;
            #pragma unroll
            for (int i = 0; i < 4; i++)
                trs[wr * 2048 + (qd * 4 + i) * 128 + lcol] = f2bf(acc[mt][nt][i] + bb[nt]);
        }
        __syncthreads();
        int rl = tid >> 4, cc = (tid & 15) * 8;
        int g0 = rowbase + mt * 16 + rl;
        int g1 = rowbase + 64 + mt * 16 + rl;
        if (g0 < MV)
            *(uint4*)(kv + (size_t)g0 * 512 + col0 + cc) = *(const uint4*)(trs + rl * 128 + cc);
        if (g1 < MV)
            *(uint4*)(kv + (size_t)g1 * 512 + col0 + cc) = *(const uint4*)(trs + 2048 + rl * 128 + cc);
    }
}

// ---------------------------------------------------------------------------
// k_mm<KD,EPI>: plain row GEMM, A[8192][KD] bf16 @ Bt[cols][KD] bf16.
//   EPI 0: relu -> bf16 at ld FFD (FF1)   EPI 1: +bias+res -> fp32 (FF2)
//   EPI 2: +bias+res[qidx[row]] -> fp32 (proj)
// ---------------------------------------------------------------------------
template <int KD, int EPI>
__global__ __launch_bounds__(256) void k_mm(const unsigned short* __restrict__ A,
                                            const unsigned short* __restrict__ Bt_g,
                                            const float* __restrict__ bias,
                                            const float* __restrict__ res,
                                            const int* __restrict__ qidx,
                                            unsigned short* __restrict__ out_bf,
                                            float* __restrict__ out_f) {
    __shared__ __align__(16) unsigned short As[128 * ASTR];
    __shared__ __align__(16) unsigned short Bs[64 * ASTR];
    int tid = threadIdx.x;
    int w = tid >> 6, l = tid & 63;
    int rowbase = blockIdx.y * 128;
    int col0 = blockIdx.x * 64;
    int r0 = tid >> 2, qt = tid & 3;
    const unsigned short* a0p = A + (size_t)(rowbase + r0) * KD + qt * 8;
    const unsigned short* a1p = A + (size_t)(rowbase + 64 + r0) * KD + qt * 8;

    f32x4 acc[2][4];
    #pragma unroll
    for (int mt = 0; mt < 2; mt++)
        #pragma unroll
        for (int nt = 0; nt < 4; nt++)
            acc[mt][nt] = (f32x4){0.f, 0.f, 0.f, 0.f};

    const int ml = l & 15, qd = l >> 4;
    for (int kk = 0; kk < KD; kk += 32) {
        __syncthreads();
        uint4 v0 = *(const uint4*)(a0p + kk);
        uint4 v1 = *(const uint4*)(a1p + kk);
        *(uint4*)(As + r0 * ASTR + qt * 8)        = v0;
        *(uint4*)(As + (64 + r0) * ASTR + qt * 8) = v1;
        {
            uint4 bv = *(const uint4*)(Bt_g + (size_t)(col0 + r0) * KD + kk + qt * 8);
            *(uint4*)(Bs + r0 * ASTR + qt * 8) = bv;
        }
        __syncthreads();
        bf16x8 a0 = *(const bf16x8*)(As + (w * 32 + ml) * ASTR + qd * 8);
        bf16x8 a1 = *(const bf16x8*)(As + (w * 32 + 16 + ml) * ASTR + qd * 8);
        #pragma unroll
        for (int nt = 0; nt < 4; nt++) {
            bf16x8 bb = *(const bf16x8*)(Bs + (nt * 16 + ml) * ASTR + qd * 8);
            acc[0][nt] = __builtin_amdgcn_mfma_f32_16x16x32_bf16(a0, bb, acc[0][nt], 0, 0, 0);
            acc[1][nt] = __builtin_amdgcn_mfma_f32_16x16x32_bf16(a1, bb, acc[1][nt], 0, 0, 0);
        }
    }

    #pragma unroll
    for (int nt = 0; nt < 4; nt++) {
        int col = col0 + nt * 16 + ml;
        float bv = bias[col];
        #pragma unroll
        for (int mt = 0; mt < 2; mt++) {
            int rl = w * 32 + mt * 16 + qd * 4;
            #pragma unroll
            for (int i = 0; i < 4; i++) {
                int row = rowbase + rl + i;
                float v = acc[mt][nt][i] + bv;
                if (EPI == 0) {
                    out_bf[(size_t)row * FFD + col] = f2bf(fmaxf(v, 0.f));
                } else if (EPI == 1) {
                    out_f[(size_t)row * CH + col] = v + res[(size_t)row * CH + col];
                } else {
                    int qi = qidx[row];
                    out_f[(size_t)row * CH + col] = v + res[(size_t)qi * CH + col];
                }
            }
        }
    }
}

// ---------------------------------------------------------------------------
// k_attn: logits = q.k*DH^-0.5 + qp gathers + dot(k, comb-row); mask -> e=0;
// softmax over K. k rows gathered from dense kv via gidx.
// ---------------------------------------------------------------------------
__global__ __launch_bounds__(256) void k_attn(const float* __restrict__ qbuf,
                                              const float* __restrict__ qp,
                                              const unsigned short* __restrict__ kvmat,
                                              const int* __restrict__ gidx,
                                              const int* __restrict__ mask_i,
                                              const int* __restrict__ rel_x,
                                              const int* __restrict__ rel_y,
                                              const int* __restrict__ rel_z,
                                              const float* __restrict__ comb,
                                              float* __restrict__ attn) {
    __shared__ float q_s[1024];
    __shared__ float qp_s[4 * QPN];
    int tid = threadIdx.x;
    int qb = blockIdx.x * 4;
    for (int i = tid; i < 1024; i += 256) q_s[i] = qbuf[(size_t)qb * CH + i];
    for (int i = tid; i < 4 * QPN; i += 256) qp_s[i] = qp[(size_t)qb * QPN + i];
    __syncthreads();
    int h = tid >> 5, k = tid & 31;
    const float scale = 0.17677669529663687f;   // 32^-0.5
    for (int qq = 0; qq < 4; qq++) {
        int n = qb + qq;
        int gi = n * KN + k;
        int mk = mask_i[gi];
        float lg = -1e9f;
        if (!mk) {
            int rx = rel_x[gi], ry = rel_y[gi], rz = rel_z[gi];
            int g = gidx[gi];
            const uint4* kp = (const uint4*)(kvmat + (size_t)g * 512 + h * DHD);
            float kv[32];
            #pragma unroll
            for (int j = 0; j < 4; j++) {
                uint4 u = kp[j];
                kv[j * 8 + 0] = bf2f((unsigned short)(u.x & 0xFFFF));
                kv[j * 8 + 1] = bf2f((unsigned short)(u.x >> 16));
                kv[j * 8 + 2] = bf2f((unsigned short)(u.y & 0xFFFF));
                kv[j * 8 + 3] = bf2f((unsigned short)(u.y >> 16));
                kv[j * 8 + 4] = bf2f((unsigned short)(u.z & 0xFFFF));
                kv[j * 8 + 5] = bf2f((unsigned short)(u.z >> 16));
                kv[j * 8 + 6] = bf2f((unsigned short)(u.w & 0xFFFF));
                kv[j * 8 + 7] = bf2f((unsigned short)(u.w >> 16));
            }
            const float* cp = comb + ((((h * 15 + rx) * 15 + ry) * 7 + rz) << 5);
            float s1 = 0.f, s2 = 0.f;
            const float* qrow = q_s + qq * CH + h * DHD;
            #pragma unroll
            for (int d = 0; d < 32; d++) {
                s1 += kv[d] * qrow[d];
                s2 += kv[d] * cp[d];
            }
            lg = s1 * scale + s2
               + qp_s[qq * QPN + h * QPW + rx]
               + qp_s[qq * QPN + h * QPW + 15 + ry]
               + qp_s[qq * QPN + h * QPW + 30 + rz];
        }
        float mx = lg;
        #pragma unroll
        for (int off = 1; off <= 16; off <<= 1) mx = fmaxf(mx, __shfl_xor(mx, off));
        float e = mk ? 0.f : __expf(lg - mx);
        float sm = e;
        #pragma unroll
        for (int off = 1; off <= 16; off <<= 1) sm += __shfl_xor(sm, off);
        attn[(size_t)n * 256 + tid] = (sm > 0.f) ? e / sm : 0.f;
    }
}

// ---------------------------------------------------------------------------
// k_av: attnln[n][c] = bf16( sum_k attn[n,h(c),k] * v[gidx[n,k]][c] ),
// v rows include b_v (softmax sums to 1 over unmasked -> bias correct);
// all-masked queries emit b_v (matches reference's uniform softmax over
// b_v rows). One wave per query; lane covers 4 cols (8B coalesced rows).
// ---------------------------------------------------------------------------
__global__ __launch_bounds__(256) void k_av(const unsigned short* __restrict__ kvmat,
                                            const int* __restrict__ gidx,
                                            const int* __restrict__ mask_i,
                                            const float* __restrict__ attn,
                                            const float* __restrict__ b_v,
                                            unsigned short* __restrict__ attnln) {
    __shared__ float attn_s[4 * 256];
    __shared__ int mask_s[4 * 32];
    int tid = threadIdx.x;
    int w = tid >> 6, l = tid & 63;
    int qb = blockIdx.x * 4;
    for (int i = tid; i < 1024; i += 256) attn_s[i] = attn[(size_t)qb * 256 + i];
    if (tid < 128) mask_s[tid] = mask_i[qb * 32 + tid];
    __syncthreads();
    int n = qb + w;
    int h = l >> 3;                         // (l*4)>>5
    float a0 = 0.f, a1 = 0.f, a2 = 0.f, a3 = 0.f;
    int nm = 0;
    for (int k = 0; k < KN; k++) {
        if (mask_s[w * 32 + k]) continue;   // wave-uniform branch
        nm++;
        int g = gidx[n * 32 + k];
        ushort4 v4 = *(const ushort4*)(kvmat + (size_t)g * 512 + 256 + l * 4);
        float av = attn_s[w * 256 + h * 32 + k];
        a0 += av * bf2f(v4.x);
        a1 += av * bf2f(v4.y);
        a2 += av * bf2f(v4.z);
        a3 += av * bf2f(v4.w);
    }
    int col = l * 4;
    if (nm == 0) {
        a0 = b_v[col]; a1 = b_v[col + 1]; a2 = b_v[col + 2]; a3 = b_v[col + 3];
    }
    ushort4 o;
    o.x = f2bf(a0); o.y = f2bf(a1); o.z = f2bf(a2); o.w = f2bf(a3);
    *(ushort4*)(attnln + (size_t)n * CH + col) = o;
}

// ---------------------------------------------------------------------------
extern "C" void kernel_launch(void* const* d_in, const int* in_sizes, int n_in,
                              void* d_out, int out_size, void* d_ws, size_t ws_size,
                              hipStream_t stream) {
    (void)in_sizes; (void)n_in; (void)out_size; (void)ws_size;
    const float* vox    = (const float*)d_in[0];
    const float* coords = (const float*)d_in[1];
    const int*   qidx   = (const int*)d_in[2];
    const int*   gidx   = (const int*)d_in[3];
    const void*  mraw   = d_in[4];
    const int*   rel_x  = (const int*)d_in[5];
    const int*   rel_y  = (const int*)d_in[6];
    const int*   rel_z  = (const int*)d_in[7];
    const float* w_pos  = (const float*)d_in[8];
    const float* b_pos  = (const float*)d_in[9];
    const float* w_q    = (const float*)d_in[10];
    const float* b_q    = (const float*)d_in[11];
    const float* w_k    = (const float*)d_in[12];
    const float* b_k    = (const float*)d_in[13];
    const float* w_v    = (const float*)d_in[14];
    const float* b_v    = (const float*)d_in[15];
    const float* w_proj = (const float*)d_in[16];
    const float* b_proj = (const float*)d_in[17];
    const float* ln1_g  = (const float*)d_in[18];
    const float* ln1_b  = (const float*)d_in[19];
    const float* ln2_g  = (const float*)d_in[20];
    const float* ln2_b  = (const float*)d_in[21];
    const float* w_ff1  = (const float*)d_in[22];
    const float* b_ff1  = (const float*)d_in[23];
    const float* w_ff2  = (const float*)d_in[24];
    const float* b_ff2  = (const float*)d_in[25];
    const float* pos_qx = (const float*)d_in[26];
    const float* pos_qy = (const float*)d_in[27];
    const float* pos_qz = (const float*)d_in[28];
    const float* pos_kx = (const float*)d_in[29];
    const float* pos_ky = (const float*)d_in[30];
    const float* pos_kz = (const float*)d_in[31];

    // workspace carve (~210 MB total)
    char* p = (char*)d_ws;
    auto take = [&](size_t n) { char* r = p; p += (n + 255) & ~(size_t)255; return r; };
    unsigned short* ln_x    = (unsigned short*)take((size_t)MV * CH * 2);   // 51.2 MB
    unsigned short* w_kv_t  = (unsigned short*)take((size_t)512 * 256 * 2);
    unsigned short* w1_t    = (unsigned short*)take((size_t)512 * 256 * 2);
    unsigned short* w2_t    = (unsigned short*)take((size_t)256 * 512 * 2);
    unsigned short* wp_t    = (unsigned short*)take((size_t)256 * 256 * 2);
    float*          bkv     = (float*)take(512 * 4);
    int*            flags   = (int*)take(64 * 4);
    int*            mask_i  = (int*)take((size_t)NG * 4);                   // 1.05 MB
    float*          comb    = (float*)take((size_t)8 * 15 * 15 * 7 * 32 * 4); // 1.6 MB
    float*          qbuf    = (float*)take((size_t)NQ * CH * 4);            // 8.4 MB
    float*          qp      = (float*)take((size_t)NQ * QPN * 4);           // 9.7 MB
    unsigned short* kvmat   = (unsigned short*)take((size_t)MV * 512 * 2);  // 102.4 MB
    float*          attn    = (float*)take((size_t)NQ * 256 * 4);           // 8.4 MB
    unsigned short* attnln  = (unsigned short*)take((size_t)NQ * CH * 2);   // 4.2 MB
    float*          actbuf  = (float*)take((size_t)NQ * CH * 4);            // 8.4 MB
    unsigned short* actln   = (unsigned short*)take((size_t)NQ * CH * 2);   // 4.2 MB
    unsigned short* hbuf    = (unsigned short*)take((size_t)NQ * FFD * 2);  // 8.4 MB

    hipLaunchKernelGGL(k_detect_mask, dim3(64), dim3(256), 0, stream,
                       (const unsigned char*)mraw, flags);
    hipLaunchKernelGGL(k_prep, dim3(NG / 256), dim3(256), 0, stream,
                       w_k, w_v, w_ff1, w_ff2, w_proj, b_k, b_v, mraw, flags,
                       w_kv_t, w1_t, w2_t, wp_t, bkv, mask_i);
    hipLaunchKernelGGL(k_posc, dim3((8 * 15 * 15 * 7 * 32 + 255) / 256), dim3(256), 0, stream,
                       pos_kx, pos_ky, pos_kz, comb);
    hipLaunchKernelGGL(k_ln, dim3(MV / 4 + 1), dim3(256), 0, stream,
                       vox, ln1_g, ln1_b, ln_x, MV);
    hipLaunchKernelGGL(k_q, dim3(NQ / 8), dim3(256), 0, stream,
                       ln_x, coords, qidx, w_pos, b_pos, w_q, b_q,
                       pos_qx, pos_qy, pos_qz, qbuf, qp);
    // dense kv projection: kv[m][512] = ln_x @ [w_k|w_v] + [b_k|b_v]
    hipLaunchKernelGGL(k_kv, dim3(4, (MV + 127) / 128), dim3(256), 0, stream,
                       ln_x, w_kv_t, bkv, kvmat);
    hipLaunchKernelGGL(k_attn, dim3(NQ / 4), dim3(256), 0, stream,
                       qbuf, qp, kvmat, gidx, mask_i, rel_x, rel_y, rel_z, comb, attn);
    hipLaunchKernelGGL(k_av, dim3(NQ / 4), dim3(256), 0, stream,
                       kvmat, gidx, mask_i, attn, b_v, attnln);
    // proj: act = attn_bf16 @ wp_t + b_proj + vox[qidx]
    hipLaunchKernelGGL(HIP_KERNEL_NAME(k_mm<256, 2>), dim3(4, NQ / 128), dim3(256), 0, stream,
                       attnln, wp_t, b_proj, vox, qidx,
                       (unsigned short*)nullptr, actbuf);
    hipLaunchKernelGGL(k_ln, dim3(NQ / 4), dim3(256), 0, stream,
                       actbuf, ln2_g, ln2_b, actln, NQ);
    // FF1: h = relu(actln @ w1_t + b_ff1)
    hipLaunchKernelGGL(HIP_KERNEL_NAME(k_mm<256, 0>), dim3(8, NQ / 128), dim3(256), 0, stream,
                       actln, w1_t, b_ff1, (const float*)nullptr, (const int*)nullptr,
                       hbuf, (float*)nullptr);
    // FF2: out = h @ w2_t + b_ff2 + act
    hipLaunchKernelGGL(HIP_KERNEL_NAME(k_mm<512, 1>), dim3(4, NQ / 128), dim3(256), 0, stream,
                       hbuf, w2_t, b_ff2, actbuf, (const int*)nullptr,
                       (unsigned short*)nullptr, (float*)d_out);
}

// Round 7
// 406.330 us; speedup vs baseline: 1.4201x; 1.1243x over previous
//
#include <hip/hip_runtime.h>
#include <hip/hip_bf16.h>
#include <math.h>

// Problem constants (fixed by the reference)
#define MV   100000          // voxels
#define NQ   8192            // queries
#define KN   32              // neighbors per query
#define CH   256             // channels
#define NH   8               // heads
#define DHD  32              // head dim
#define FFD  512             // FF hidden
#define NG   (NQ*KN)         // 262144 gathered rows
#define QPW  37              // 15+15+7 rel-pos columns per head (q-side)
#define QPN  (NH*QPW)        // 296
#define QPL  320             // padded qp row stride (multiple of 64)
#define ASTR 40              // padded LDS stride for k_mm

typedef __bf16 bf16x8 __attribute__((ext_vector_type(8)));
typedef float  f32x4  __attribute__((ext_vector_type(4)));

__device__ __forceinline__ float bf2f(unsigned short u) {
    return __uint_as_float(((unsigned int)u) << 16);
}
__device__ __forceinline__ unsigned short f2bf(float f) {
    unsigned int x = __float_as_uint(f);
    unsigned int r = x + 0x7FFFu + ((x >> 16) & 1u);   // RNE
    return (unsigned short)(r >> 16);
}
// async global->LDS, 16 B per lane; LDS dest = wave-uniform base + lane*16
__device__ __forceinline__ void glds16(const unsigned short* g, unsigned short* l) {
    __builtin_amdgcn_global_load_lds(
        (const __attribute__((address_space(1))) void*)g,
        (__attribute__((address_space(3))) void*)l, 16, 0, 0);
}

// ---------------------------------------------------------------------------
// k_detect_mask: gather_mask may ship as int32 (0/1) or raw 1-byte bools.
// ---------------------------------------------------------------------------
__global__ __launch_bounds__(256) void k_detect_mask(const unsigned char* __restrict__ raw,
                                                     int* __restrict__ flags) {
    __shared__ int any;
    if (threadIdx.x == 0) any = 0;
    __syncthreads();
    const uint4* p = (const uint4*)raw;             // NG bytes = 16384 uint4
    int i = blockIdx.x * 256 + threadIdx.x;
    uint4 v = p[i];
    if ((v.x | v.y | v.z | v.w) & 0xFFFFFF00u) any = 1;
    __syncthreads();
    if (threadIdx.x == 0) flags[blockIdx.x] = any;
}

// ---------------------------------------------------------------------------
// k_prep: int mask (layout-adaptive) + bf16 col-major (B-layout) weights:
//   w_kv_t[512][256], w1_t[512][256], w2_t[256][512], wp_t[256][256],
//   wq_t[256][256], wqp_t[320][256] (block-diagonal q-side rel-pos weight),
//   bkv = [b_k|b_v], zbias[320] = 0.
// ---------------------------------------------------------------------------
__global__ __launch_bounds__(256) void k_prep(const float* __restrict__ w_k,
                                              const float* __restrict__ w_v,
                                              const float* __restrict__ w_ff1,
                                              const float* __restrict__ w_ff2,
                                              const float* __restrict__ w_proj,
                                              const float* __restrict__ w_q,
                                              const float* __restrict__ b_k,
                                              const float* __restrict__ b_v,
                                              const float* __restrict__ pos_qx,
                                              const float* __restrict__ pos_qy,
                                              const float* __restrict__ pos_qz,
                                              const void* __restrict__ mask_raw,
                                              const int* __restrict__ flags,
                                              unsigned short* __restrict__ w_kv_t,
                                              unsigned short* __restrict__ w1_t,
                                              unsigned short* __restrict__ w2_t,
                                              unsigned short* __restrict__ wp_t,
                                              unsigned short* __restrict__ wq_t,
                                              unsigned short* __restrict__ wqp_t,
                                              float* __restrict__ bkv,
                                              float* __restrict__ zbias,
                                              int* __restrict__ mask_i) {
    __shared__ int bl;
    if (threadIdx.x == 0) {
        int a = 0;
        #pragma unroll 8
        for (int i = 0; i < 64; i++) a |= flags[i];
        bl = a;
    }
    __syncthreads();
    int byteLayout = bl;
    int idx = blockIdx.x * 256 + threadIdx.x;       // grid 1024 -> 262144
    if (blockIdx.x == 0 && threadIdx.x < 512)
        bkv[threadIdx.x] = (threadIdx.x < 256) ? b_k[threadIdx.x]
                                               : b_v[threadIdx.x - 256];
    if (idx < QPL) zbias[idx] = 0.f;
    if (idx < NG) {
        int mv = byteLayout ? (int)((const unsigned char*)mask_raw)[idx]
                            : ((const int*)mask_raw)[idx];
        mask_i[idx] = (mv != 0) ? 1 : 0;
    }
    if (idx < 512 * 256) {
        int col = idx >> 8, j = idx & 255;
        float v = (col < 256) ? w_k[j * 256 + col] : w_v[j * 256 + (col - 256)];
        w_kv_t[idx] = f2bf(v);
    }
    if (idx < 512 * 256) {
        int n = idx >> 8, k = idx & 255;
        w1_t[idx] = f2bf(w_ff1[k * FFD + n]);
    }
    if (idx < 256 * 512) {
        int n = idx >> 9, k = idx & 511;
        w2_t[idx] = f2bf(w_ff2[k * CH + n]);
    }
    if (idx < 256 * 256) {
        int n = idx >> 8, k = idx & 255;
        wp_t[idx] = f2bf(w_proj[k * CH + n]);
        wq_t[idx] = f2bf(w_q[k * CH + n]);
    }
    if (idx < QPL * 256) {                          // wqp_t[col][k]
        int col = idx >> 8, k = idx & 255;
        float v = 0.f;
        if (col < QPN) {
            int h = col / QPW, r = col % QPW;
            int h2 = k >> 5, d = k & 31;
            if (h2 == h) {
                if (r < 15)      v = pos_qx[(h * DHD + d) * 15 + r];
                else if (r < 30) v = pos_qy[(h * DHD + d) * 15 + (r - 15)];
                else             v = pos_qz[(h * DHD + d) * 7  + (r - 30)];
            }
        }
        wqp_t[idx] = f2bf(v);
    }
}

// ---------------------------------------------------------------------------
// k_posc: comb[h][rx][ry][rz][d] = pos_kx[h][d][rx]+pos_ky[h][d][ry]+pos_kz[h][d][rz]
// ---------------------------------------------------------------------------
__global__ __launch_bounds__(256) void k_posc(const float* __restrict__ pos_kx,
                                              const float* __restrict__ pos_ky,
                                              const float* __restrict__ pos_kz,
                                              float* __restrict__ comb) {
    int idx = blockIdx.x * 256 + threadIdx.x;
    if (idx >= 8 * 15 * 15 * 7 * 32) return;
    int d = idx & 31, r = idx >> 5;
    int rz = r % 7;  r /= 7;
    int ry = r % 15; r /= 15;
    int rx = r % 15; int h = r / 15;
    comb[idx] = pos_kx[(h * DHD + d) * 15 + rx]
              + pos_ky[(h * DHD + d) * 15 + ry]
              + pos_kz[(h * DHD + d) * 7  + rz];
}

// ---------------------------------------------------------------------------
// k_ln: LayerNorm rows of x[nrows][256] -> bf16. One wave per row.
// ---------------------------------------------------------------------------
__global__ __launch_bounds__(256) void k_ln(const float* __restrict__ x,
                                            const float* __restrict__ g,
                                            const float* __restrict__ b,
                                            unsigned short* __restrict__ o,
                                            int nrows) {
    int wid = threadIdx.x >> 6, lane = threadIdx.x & 63;
    int row = blockIdx.x * 4 + wid;
    if (row >= nrows) return;
    const float4 v = *(const float4*)(x + (size_t)row * CH + lane * 4);
    float s  = v.x + v.y + v.z + v.w;
    float sq = v.x * v.x + v.y * v.y + v.z * v.z + v.w * v.w;
    #pragma unroll
    for (int off = 1; off < 64; off <<= 1) {
        s  += __shfl_xor(s,  off);
        sq += __shfl_xor(sq, off);
    }
    float mu  = s * (1.f / CH);
    float var = sq * (1.f / CH) - mu * mu;
    float rs  = rsqrtf(var + 1e-5f);
    float4 gv = *(const float4*)(g + lane * 4);
    float4 bv = *(const float4*)(b + lane * 4);
    ushort4 ov;
    ov.x = f2bf((v.x - mu) * rs * gv.x + bv.x);
    ov.y = f2bf((v.y - mu) * rs * gv.y + bv.y);
    ov.z = f2bf((v.z - mu) * rs * gv.z + bv.z);
    ov.w = f2bf((v.w - mu) * rs * gv.w + bv.w);
    *(ushort4*)(o + (size_t)row * CH + lane * 4) = ov;
}

// ---------------------------------------------------------------------------
// k_qin: q_in[n][c] = bf16( ln_x[qidx[n]][c] + relu(coords[n]@w_pos + b_pos) )
// 8 queries per block, thread = channel.
// ---------------------------------------------------------------------------
__global__ __launch_bounds__(256) void k_qin(const unsigned short* __restrict__ ln_x,
                                             const float* __restrict__ coords,
                                             const int* __restrict__ qidx,
                                             const float* __restrict__ w_pos,
                                             const float* __restrict__ b_pos,
                                             unsigned short* __restrict__ qin) {
    int c = threadIdx.x;
    int nb = blockIdx.x * 8;
    float wp0 = w_pos[c], wp1 = w_pos[CH + c], wp2 = w_pos[2 * CH + c], bp = b_pos[c];
    #pragma unroll
    for (int qq = 0; qq < 8; qq++) {
        int n = nb + qq;
        float p = bp + coords[n * 3] * wp0 + coords[n * 3 + 1] * wp1 + coords[n * 3 + 2] * wp2;
        p = fmaxf(p, 0.f);
        int qi = qidx[n];
        qin[(size_t)n * CH + c] = f2bf(bf2f(ln_x[(size_t)qi * CH + c]) + p);
    }
}

// ---------------------------------------------------------------------------
// k_kv: DENSE projection of all voxels: kv[m][0:256]=ln_x@w_k+b_k,
// kv[m][256:512]=ln_x@w_v+b_v, bf16. Tile 128x128 (glds16 staging).
// Epilogue: LDS transpose -> coalesced 16B stores.
// ---------------------------------------------------------------------------
__global__ __launch_bounds__(256) void k_kv(const unsigned short* __restrict__ ln_x,
                                            const unsigned short* __restrict__ w_kv_t,
                                            const float* __restrict__ bkv,
                                            unsigned short* __restrict__ kv) {
    __shared__ __align__(16) unsigned short As[128 * 32];   // 8 KB
    __shared__ __align__(16) unsigned short Bs[128 * 32];   // 8 KB
    const int tid = threadIdx.x;
    const int w = tid >> 6, l = tid & 63;
    const int wr = w >> 1, wc = w & 1;
    const int rowbase = blockIdx.y * 128;
    const int col0 = blockIdx.x * 128;
    const int sr = l >> 2, sq = l & 3;
    int ra0 = rowbase + w * 16 + sr;      if (ra0 >= MV) ra0 = MV - 1;
    int ra1 = rowbase + 64 + w * 16 + sr; if (ra1 >= MV) ra1 = MV - 1;
    const unsigned short* pa0 = ln_x + (size_t)ra0 * CH + sq * 8;
    const unsigned short* pa1 = ln_x + (size_t)ra1 * CH + sq * 8;
    const unsigned short* pb0 = w_kv_t + (size_t)(col0 + w * 16 + sr) * CH + sq * 8;
    const unsigned short* pb1 = w_kv_t + (size_t)(col0 + 64 + w * 16 + sr) * CH + sq * 8;
    unsigned short* lA0 = As + w * 512;
    unsigned short* lA1 = As + 2048 + w * 512;
    unsigned short* lB0 = Bs + w * 512;
    unsigned short* lB1 = Bs + 2048 + w * 512;

    f32x4 acc[4][4];
    #pragma unroll
    for (int mt = 0; mt < 4; mt++)
        #pragma unroll
        for (int nt = 0; nt < 4; nt++)
            acc[mt][nt] = (f32x4){0.f, 0.f, 0.f, 0.f};

    const int ml = l & 15, qd = l >> 4;
    for (int kk = 0; kk < CH; kk += 32) {
        __syncthreads();
        glds16(pa0 + kk, lA0);
        glds16(pa1 + kk, lA1);
        glds16(pb0 + kk, lB0);
        glds16(pb1 + kk, lB1);
        __syncthreads();
        bf16x8 af[4], bf[4];
        #pragma unroll
        for (int mt = 0; mt < 4; mt++)
            af[mt] = *(const bf16x8*)(As + (wr * 64 + mt * 16 + ml) * 32 + qd * 8);
        #pragma unroll
        for (int nt = 0; nt < 4; nt++)
            bf[nt] = *(const bf16x8*)(Bs + (wc * 64 + nt * 16 + ml) * 32 + qd * 8);
        #pragma unroll
        for (int mt = 0; mt < 4; mt++)
            #pragma unroll
            for (int nt = 0; nt < 4; nt++)
                acc[mt][nt] = __builtin_amdgcn_mfma_f32_16x16x32_bf16(af[mt], bf[nt], acc[mt][nt], 0, 0, 0);
    }

    // epilogue: per-col bias, then LDS transpose -> coalesced 16B stores
    float bb[4];
    #pragma unroll
    for (int nt = 0; nt < 4; nt++)
        bb[nt] = bkv[col0 + wc * 64 + nt * 16 + ml];
    unsigned short* trs = As;                 // reuse 8 KB (2 bands x 16 x 128)
    #pragma unroll
    for (int mt = 0; mt < 4; mt++) {
        __syncthreads();                      // protect As reuse / prev pass
        #pragma unroll
        for (int nt = 0; nt < 4; nt++) {
            int lcol = wc * 64 + nt * 16 + ml;
            #pragma unroll
            for (int i = 0; i < 4; i++)
                trs[wr * 2048 + (qd * 4 + i) * 128 + lcol] = f2bf(acc[mt][nt][i] + bb[nt]);
        }
        __syncthreads();
        int rl = tid >> 4, cc = (tid & 15) * 8;
        int g0 = rowbase + mt * 16 + rl;
        int g1 = rowbase + 64 + mt * 16 + rl;
        if (g0 < MV)
            *(uint4*)(kv + (size_t)g0 * 512 + col0 + cc) = *(const uint4*)(trs + rl * 128 + cc);
        if (g1 < MV)
            *(uint4*)(kv + (size_t)g1 * 512 + col0 + cc) = *(const uint4*)(trs + 2048 + rl * 128 + cc);
    }
}

// ---------------------------------------------------------------------------
// k_mm<KD,EPI,LDO>: row GEMM, A[8192][KD] bf16 @ Bt[cols][KD] bf16.
//   EPI 0: relu -> bf16 at ld LDO            (FF1)
//   EPI 1: +bias+res -> fp32 at ld CH        (FF2)
//   EPI 2: +bias+res[qidx[row]] -> fp32      (proj)
//   EPI 3: +bias -> fp32 AND bf16 at ld CH   (q projection)
//   EPI 4: +bias -> fp32 at ld LDO           (qp tables)
// ---------------------------------------------------------------------------
template <int KD, int EPI, int LDO>
__global__ __launch_bounds__(256) void k_mm(const unsigned short* __restrict__ A,
                                            const unsigned short* __restrict__ Bt_g,
                                            const float* __restrict__ bias,
                                            const float* __restrict__ res,
                                            const int* __restrict__ qidx,
                                            unsigned short* __restrict__ out_bf,
                                            float* __restrict__ out_f) {
    __shared__ __align__(16) unsigned short As[128 * ASTR];
    __shared__ __align__(16) unsigned short Bs[64 * ASTR];
    int tid = threadIdx.x;
    int w = tid >> 6, l = tid & 63;
    int rowbase = blockIdx.y * 128;
    int col0 = blockIdx.x * 64;
    int r0 = tid >> 2, qt = tid & 3;
    const unsigned short* a0p = A + (size_t)(rowbase + r0) * KD + qt * 8;
    const unsigned short* a1p = A + (size_t)(rowbase + 64 + r0) * KD + qt * 8;

    f32x4 acc[2][4];
    #pragma unroll
    for (int mt = 0; mt < 2; mt++)
        #pragma unroll
        for (int nt = 0; nt < 4; nt++)
            acc[mt][nt] = (f32x4){0.f, 0.f, 0.f, 0.f};

    const int ml = l & 15, qd = l >> 4;
    for (int kk = 0; kk < KD; kk += 32) {
        __syncthreads();
        uint4 v0 = *(const uint4*)(a0p + kk);
        uint4 v1 = *(const uint4*)(a1p + kk);
        *(uint4*)(As + r0 * ASTR + qt * 8)        = v0;
        *(uint4*)(As + (64 + r0) * ASTR + qt * 8) = v1;
        {
            uint4 bv = *(const uint4*)(Bt_g + (size_t)(col0 + r0) * KD + kk + qt * 8);
            *(uint4*)(Bs + r0 * ASTR + qt * 8) = bv;
        }
        __syncthreads();
        bf16x8 a0 = *(const bf16x8*)(As + (w * 32 + ml) * ASTR + qd * 8);
        bf16x8 a1 = *(const bf16x8*)(As + (w * 32 + 16 + ml) * ASTR + qd * 8);
        #pragma unroll
        for (int nt = 0; nt < 4; nt++) {
            bf16x8 bb = *(const bf16x8*)(Bs + (nt * 16 + ml) * ASTR + qd * 8);
            acc[0][nt] = __builtin_amdgcn_mfma_f32_16x16x32_bf16(a0, bb, acc[0][nt], 0, 0, 0);
            acc[1][nt] = __builtin_amdgcn_mfma_f32_16x16x32_bf16(a1, bb, acc[1][nt], 0, 0, 0);
        }
    }

    #pragma unroll
    for (int nt = 0; nt < 4; nt++) {
        int col = col0 + nt * 16 + ml;
        float bv = bias[col];
        #pragma unroll
        for (int mt = 0; mt < 2; mt++) {
            int rl = w * 32 + mt * 16 + qd * 4;
            #pragma unroll
            for (int i = 0; i < 4; i++) {
                int row = rowbase + rl + i;
                float v = acc[mt][nt][i] + bv;
                if (EPI == 0) {
                    out_bf[(size_t)row * LDO + col] = f2bf(fmaxf(v, 0.f));
                } else if (EPI == 1) {
                    out_f[(size_t)row * CH + col] = v + res[(size_t)row * CH + col];
                } else if (EPI == 2) {
                    int qi = qidx[row];
                    out_f[(size_t)row * CH + col] = v + res[(size_t)qi * CH + col];
                } else if (EPI == 3) {
                    out_f[(size_t)row * CH + col] = v;
                    out_bf[(size_t)row * CH + col] = f2bf(v);
                } else {
                    out_f[(size_t)row * LDO + col] = v;
                }
            }
        }
    }
}

// ---------------------------------------------------------------------------
// k_attn: logits = q.k*DH^-0.5 + qp gathers + dot(k, comb-row); mask -> e=0;
// softmax over K. k rows gathered from dense kv via gidx. qp ld = QPL.
// ---------------------------------------------------------------------------
__global__ __launch_bounds__(256) void k_attn(const float* __restrict__ qbuf,
                                              const float* __restrict__ qp,
                                              const unsigned short* __restrict__ kvmat,
                                              const int* __restrict__ gidx,
                                              const int* __restrict__ mask_i,
                                              const int* __restrict__ rel_x,
                                              const int* __restrict__ rel_y,
                                              const int* __restrict__ rel_z,
                                              const float* __restrict__ comb,
                                              float* __restrict__ attn) {
    __shared__ float q_s[1024];
    __shared__ float qp_s[4 * QPL];
    int tid = threadIdx.x;
    int qb = blockIdx.x * 4;
    for (int i = tid; i < 1024; i += 256) q_s[i] = qbuf[(size_t)qb * CH + i];
    for (int i = tid; i < 4 * QPL; i += 256) qp_s[i] = qp[(size_t)qb * QPL + i];
    __syncthreads();
    int h = tid >> 5, k = tid & 31;
    const float scale = 0.17677669529663687f;   // 32^-0.5
    for (int qq = 0; qq < 4; qq++) {
        int n = qb + qq;
        int gi = n * KN + k;
        int mk = mask_i[gi];
        float lg = -1e9f;
        if (!mk) {
            int rx = rel_x[gi], ry = rel_y[gi], rz = rel_z[gi];
            int g = gidx[gi];
            const uint4* kp = (const uint4*)(kvmat + (size_t)g * 512 + h * DHD);
            float kv[32];
            #pragma unroll
            for (int j = 0; j < 4; j++) {
                uint4 u = kp[j];
                kv[j * 8 + 0] = bf2f((unsigned short)(u.x & 0xFFFF));
                kv[j * 8 + 1] = bf2f((unsigned short)(u.x >> 16));
                kv[j * 8 + 2] = bf2f((unsigned short)(u.y & 0xFFFF));
                kv[j * 8 + 3] = bf2f((unsigned short)(u.y >> 16));
                kv[j * 8 + 4] = bf2f((unsigned short)(u.z & 0xFFFF));
                kv[j * 8 + 5] = bf2f((unsigned short)(u.z >> 16));
                kv[j * 8 + 6] = bf2f((unsigned short)(u.w & 0xFFFF));
                kv[j * 8 + 7] = bf2f((unsigned short)(u.w >> 16));
            }
            const float* cp = comb + ((((h * 15 + rx) * 15 + ry) * 7 + rz) << 5);
            float s1 = 0.f, s2 = 0.f;
            const float* qrow = q_s + qq * CH + h * DHD;
            #pragma unroll
            for (int d = 0; d < 32; d++) {
                s1 += kv[d] * qrow[d];
                s2 += kv[d] * cp[d];
            }
            lg = s1 * scale + s2
               + qp_s[qq * QPL + h * QPW + rx]
               + qp_s[qq * QPL + h * QPW + 15 + ry]
               + qp_s[qq * QPL + h * QPW + 30 + rz];
        }
        float mx = lg;
        #pragma unroll
        for (int off = 1; off <= 16; off <<= 1) mx = fmaxf(mx, __shfl_xor(mx, off));
        float e = mk ? 0.f : __expf(lg - mx);
        float sm = e;
        #pragma unroll
        for (int off = 1; off <= 16; off <<= 1) sm += __shfl_xor(sm, off);
        attn[(size_t)n * 256 + tid] = (sm > 0.f) ? e / sm : 0.f;
    }
}

// ---------------------------------------------------------------------------
// k_av: attnln[n][c] = bf16( sum_k attn[n,h(c),k] * v[gidx[n,k]][c] );
// all-masked queries emit b_v. One wave per query.
// ---------------------------------------------------------------------------
__global__ __launch_bounds__(256) void k_av(const unsigned short* __restrict__ kvmat,
                                            const int* __restrict__ gidx,
                                            const int* __restrict__ mask_i,
                                            const float* __restrict__ attn,
                                            const float* __restrict__ b_v,
                                            unsigned short* __restrict__ attnln) {
    __shared__ float attn_s[4 * 256];
    __shared__ int mask_s[4 * 32];
    int tid = threadIdx.x;
    int w = tid >> 6, l = tid & 63;
    int qb = blockIdx.x * 4;
    for (int i = tid; i < 1024; i += 256) attn_s[i] = attn[(size_t)qb * 256 + i];
    if (tid < 128) mask_s[tid] = mask_i[qb * 32 + tid];
    __syncthreads();
    int n = qb + w;
    int h = l >> 3;                         // (l*4)>>5
    float a0 = 0.f, a1 = 0.f, a2 = 0.f, a3 = 0.f;
    int nm = 0;
    for (int k = 0; k < KN; k++) {
        if (mask_s[w * 32 + k]) continue;   // wave-uniform branch
        nm++;
        int g = gidx[n * 32 + k];
        ushort4 v4 = *(const ushort4*)(kvmat + (size_t)g * 512 + 256 + l * 4);
        float av = attn_s[w * 256 + h * 32 + k];
        a0 += av * bf2f(v4.x);
        a1 += av * bf2f(v4.y);
        a2 += av * bf2f(v4.z);
        a3 += av * bf2f(v4.w);
    }
    int col = l * 4;
    if (nm == 0) {
        a0 = b_v[col]; a1 = b_v[col + 1]; a2 = b_v[col + 2]; a3 = b_v[col + 3];
    }
    ushort4 o;
    o.x = f2bf(a0); o.y = f2bf(a1); o.z = f2bf(a2); o.w = f2bf(a3);
    *(ushort4*)(attnln + (size_t)n * CH + col) = o;
}

// ---------------------------------------------------------------------------
extern "C" void kernel_launch(void* const* d_in, const int* in_sizes, int n_in,
                              void* d_out, int out_size, void* d_ws, size_t ws_size,
                              hipStream_t stream) {
    (void)in_sizes; (void)n_in; (void)out_size; (void)ws_size;
    const float* vox    = (const float*)d_in[0];
    const float* coords = (const float*)d_in[1];
    const int*   qidx   = (const int*)d_in[2];
    const int*   gidx   = (const int*)d_in[3];
    const void*  mraw   = d_in[4];
    const int*   rel_x  = (const int*)d_in[5];
    const int*   rel_y  = (const int*)d_in[6];
    const int*   rel_z  = (const int*)d_in[7];
    const float* w_pos  = (const float*)d_in[8];
    const float* b_pos  = (const float*)d_in[9];
    const float* w_q    = (const float*)d_in[10];
    const float* b_q    = (const float*)d_in[11];
    const float* w_k    = (const float*)d_in[12];
    const float* b_k    = (const float*)d_in[13];
    const float* w_v    = (const float*)d_in[14];
    const float* b_v    = (const float*)d_in[15];
    const float* w_proj = (const float*)d_in[16];
    const float* b_proj = (const float*)d_in[17];
    const float* ln1_g  = (const float*)d_in[18];
    const float* ln1_b  = (const float*)d_in[19];
    const float* ln2_g  = (const float*)d_in[20];
    const float* ln2_b  = (const float*)d_in[21];
    const float* w_ff1  = (const float*)d_in[22];
    const float* b_ff1  = (const float*)d_in[23];
    const float* w_ff2  = (const float*)d_in[24];
    const float* b_ff2  = (const float*)d_in[25];
    const float* pos_qx = (const float*)d_in[26];
    const float* pos_qy = (const float*)d_in[27];
    const float* pos_qz = (const float*)d_in[28];
    const float* pos_kx = (const float*)d_in[29];
    const float* pos_ky = (const float*)d_in[30];
    const float* pos_kz = (const float*)d_in[31];

    // workspace carve (~215 MB total)
    char* p = (char*)d_ws;
    auto take = [&](size_t n) { char* r = p; p += (n + 255) & ~(size_t)255; return r; };
    unsigned short* ln_x    = (unsigned short*)take((size_t)MV * CH * 2);   // 51.2 MB
    unsigned short* w_kv_t  = (unsigned short*)take((size_t)512 * 256 * 2);
    unsigned short* w1_t    = (unsigned short*)take((size_t)512 * 256 * 2);
    unsigned short* w2_t    = (unsigned short*)take((size_t)256 * 512 * 2);
    unsigned short* wp_t    = (unsigned short*)take((size_t)256 * 256 * 2);
    unsigned short* wq_t    = (unsigned short*)take((size_t)256 * 256 * 2);
    unsigned short* wqp_t   = (unsigned short*)take((size_t)QPL * 256 * 2);
    float*          bkv     = (float*)take(512 * 4);
    float*          zbias   = (float*)take(QPL * 4);
    int*            flags   = (int*)take(64 * 4);
    int*            mask_i  = (int*)take((size_t)NG * 4);                   // 1.05 MB
    float*          comb    = (float*)take((size_t)8 * 15 * 15 * 7 * 32 * 4); // 1.6 MB
    unsigned short* qin     = (unsigned short*)take((size_t)NQ * CH * 2);   // 4.2 MB
    float*          qbuf    = (float*)take((size_t)NQ * CH * 4);            // 8.4 MB
    unsigned short* qbf     = (unsigned short*)take((size_t)NQ * CH * 2);   // 4.2 MB
    float*          qp      = (float*)take((size_t)NQ * QPL * 4);           // 10.5 MB
    unsigned short* kvmat   = (unsigned short*)take((size_t)MV * 512 * 2);  // 102.4 MB
    float*          attn    = (float*)take((size_t)NQ * 256 * 4);           // 8.4 MB
    unsigned short* attnln  = (unsigned short*)take((size_t)NQ * CH * 2);   // 4.2 MB
    float*          actbuf  = (float*)take((size_t)NQ * CH * 4);            // 8.4 MB
    unsigned short* actln   = (unsigned short*)take((size_t)NQ * CH * 2);   // 4.2 MB
    unsigned short* hbuf    = (unsigned short*)take((size_t)NQ * FFD * 2);  // 8.4 MB

    hipLaunchKernelGGL(k_detect_mask, dim3(64), dim3(256), 0, stream,
                       (const unsigned char*)mraw, flags);
    hipLaunchKernelGGL(k_prep, dim3(NG / 256), dim3(256), 0, stream,
                       w_k, w_v, w_ff1, w_ff2, w_proj, w_q, b_k, b_v,
                       pos_qx, pos_qy, pos_qz, mraw, flags,
                       w_kv_t, w1_t, w2_t, wp_t, wq_t, wqp_t, bkv, zbias, mask_i);
    hipLaunchKernelGGL(k_posc, dim3((8 * 15 * 15 * 7 * 32 + 255) / 256), dim3(256), 0, stream,
                       pos_kx, pos_ky, pos_kz, comb);
    hipLaunchKernelGGL(k_ln, dim3(MV / 4 + 1), dim3(256), 0, stream,
                       vox, ln1_g, ln1_b, ln_x, MV);
    hipLaunchKernelGGL(k_qin, dim3(NQ / 8), dim3(256), 0, stream,
                       ln_x, coords, qidx, w_pos, b_pos, qin);
    // dense kv projection: kv[m][512] = ln_x @ [w_k|w_v] + [b_k|b_v]
    hipLaunchKernelGGL(k_kv, dim3(4, (MV + 127) / 128), dim3(256), 0, stream,
                       ln_x, w_kv_t, bkv, kvmat);
    // q = qin @ wq_t + b_q  (fp32 + bf16)
    hipLaunchKernelGGL(HIP_KERNEL_NAME(k_mm<256, 3, CH>), dim3(4, NQ / 128), dim3(256), 0, stream,
                       qin, wq_t, b_q, (const float*)nullptr, (const int*)nullptr,
                       qbf, qbuf);
    // qp = qbf @ wqp_t  (fp32, ld QPL)
    hipLaunchKernelGGL(HIP_KERNEL_NAME(k_mm<256, 4, QPL>), dim3(QPL / 64, NQ / 128), dim3(256), 0, stream,
                       qbf, wqp_t, zbias, (const float*)nullptr, (const int*)nullptr,
                       (unsigned short*)nullptr, qp);
    hipLaunchKernelGGL(k_attn, dim3(NQ / 4), dim3(256), 0, stream,
                       qbuf, qp, kvmat, gidx, mask_i, rel_x, rel_y, rel_z, comb, attn);
    hipLaunchKernelGGL(k_av, dim3(NQ / 4), dim3(256), 0, stream,
                       kvmat, gidx, mask_i, attn, b_v, attnln);
    // proj: act = attn_bf16 @ wp_t + b_proj + vox[qidx]
    hipLaunchKernelGGL(HIP_KERNEL_NAME(k_mm<256, 2, CH>), dim3(4, NQ / 128), dim3(256), 0, stream,
                       attnln, wp_t, b_proj, vox, qidx,
                       (unsigned short*)nullptr, actbuf);
    hipLaunchKernelGGL(k_ln, dim3(NQ / 4), dim3(256), 0, stream,
                       actbuf, ln2_g, ln2_b, actln, NQ);
    // FF1: h = relu(actln @ w1_t + b_ff1)
    hipLaunchKernelGGL(HIP_KERNEL_NAME(k_mm<256, 0, FFD>), dim3(8, NQ / 128), dim3(256), 0, stream,
                       actln, w1_t, b_ff1, (const float*)nullptr, (const int*)nullptr,
                       hbuf, (float*)nullptr);
    // FF2: out = h @ w2_t + b_ff2 + act
    hipLaunchKernelGGL(HIP_KERNEL_NAME(k_mm<512, 1, CH>), dim3(4, NQ / 128), dim3(256), 0, stream,
                       hbuf, w2_t, b_ff2, actbuf, (const int*)nullptr,
                       (unsigned short*)nullptr, (float*)d_out);
}